// Round 24
// baseline (202.507 us; speedup 1.0000x reference)
//
#include <hip/hip_runtime.h>

#define B_ 4
#define N_ 2048
#define R_ (B_ * N_)      // 8192 rows
#define HID_ 256
#define EMB_ 64
#define IN_DIM_ 70
#define H_ 4
#define HEAD_ 64
#define FFN_ 512
#define LAYERS_ 4

typedef __attribute__((ext_vector_type(8))) short short8;
typedef __attribute__((ext_vector_type(4))) float f32x4;
typedef unsigned short ushort;
typedef unsigned char uchar;

static __device__ __forceinline__ ushort f2bf(float f) {
    unsigned u = __builtin_bit_cast(unsigned, f);
    u += 0x7fffu + ((u >> 16) & 1u);   // RNE
    return (ushort)(u >> 16);
}
static __device__ __forceinline__ float bf2f(ushort u) {
    unsigned x = ((unsigned)u) << 16;
    return __builtin_bit_cast(float, x);
}

#define GLOAD_LDS16(g, l)                                              \
    __builtin_amdgcn_global_load_lds(                                  \
        (const __attribute__((address_space(1))) void*)(g),            \
        (__attribute__((address_space(3))) void*)(l), 16, 0, 0)

#define MFMA16(a, b, c) __builtin_amdgcn_mfma_f32_16x16x32_bf16(a, b, c, 0, 0, 0)
#define MFMA8(a, b, c) __builtin_amdgcn_mfma_f32_16x16x32_fp8_fp8(a, b, c, 0, 0, 0)

// ---------------------------------------------------------------------------
// setup_all4: fused ebuild (blocks 0..2047, long pole first) + pack_weights
// (2048..2847) + input_mlp (2848..3871).
// ebuild: ONE exp2 per (i,j) — E3 = exp2(d2*ch3), then E2=E3^4, E1=E2^4,
// E0=E1^4 (2 squarings each, full-rate muls vs 1/4-rate trans). Lanes own
// 16 j -> uint4 16B stores. Trans slots/thread 512 -> 128.
// ---------------------------------------------------------------------------
__global__ __launch_bounds__(256) void setup_all4(
        const float* __restrict__ valW, const float* __restrict__ attnW,
        const float* __restrict__ ffnW1, const float* __restrict__ ffnW2,
        const float* __restrict__ outW1, ushort* __restrict__ wp,
        const float* __restrict__ xc, const float* __restrict__ emb,
        const float* __restrict__ lat, const float* __restrict__ W,
        const float* __restrict__ b, float* __restrict__ feats,
        ushort* __restrict__ featsb, uchar* __restrict__ E) {
    __shared__ __align__(16) char smem[9216];
    int blk = blockIdx.x;
    int t = threadIdx.x;

    if (blk < 2048) {
        // ---- ebuild (fp8 E): 32 i x 256 j per block ----
        float4* civ = (float4*)smem;             // 32
        float4* cjv = (float4*)(smem + 512);     // 256
        int f = blk;
        int jb = f & 7, ibl = (f >> 3) & 63, bb2 = f >> 9;
        const float* xb = xc + (size_t)bb2 * N_ * 3;
        if (t < 32) {
            const float* p = &xb[(ibl * 32 + t) * 3];
            float x = p[0], y = p[1], z = p[2];
            civ[t] = make_float4(x, y, z, x * x + y * y + z * z);
        }
        {
            const float* p = &xb[(jb * 256 + t) * 3];
            float x = p[0], y = p[1], z = p[2];
            cjv[t] = make_float4(x, y, z, x * x + y * y + z * z);
        }
        __syncthreads();
        int lane = t & 15, ig = t >> 4;          // lane: 16 j; ig: 2 i
        float4 cj[16];
#pragma unroll
        for (int e = 0; e < 16; ++e) cj[e] = cjv[lane * 16 + e];
        const float ch3 = -0.0625f * 1.44269504088896f;   // h=3: inv=1/16
        uchar* Ebase = E + ((size_t)bb2 * 2048 + ibl * 32) * 2048 + (size_t)jb * 256 + lane * 16;

#pragma unroll
        for (int r = 0; r < 2; ++r) {
            int i = ig * 2 + r;
            float4 ci = civ[i];
            float ev[16];
#pragma unroll
            for (int e = 0; e < 16; ++e) {
                float d = (ci.w + cj[e].w) -
                          2.f * (ci.x * cj[e].x + ci.y * cj[e].y + ci.z * cj[e].z);
                ev[e] = exp2f(d * ch3);
            }
            uchar* rowp = Ebase + (size_t)i * 2048;
            // store h=3, then power down: E_{h-1} = E_h^4
#pragma unroll
            for (int h = 3; h >= 0; --h) {
                int u0 = 0, u1 = 0, u2 = 0, u3 = 0;
                u0 = __builtin_amdgcn_cvt_pk_fp8_f32(ev[0], ev[1], u0, false);
                u0 = __builtin_amdgcn_cvt_pk_fp8_f32(ev[2], ev[3], u0, true);
                u1 = __builtin_amdgcn_cvt_pk_fp8_f32(ev[4], ev[5], u1, false);
                u1 = __builtin_amdgcn_cvt_pk_fp8_f32(ev[6], ev[7], u1, true);
                u2 = __builtin_amdgcn_cvt_pk_fp8_f32(ev[8], ev[9], u2, false);
                u2 = __builtin_amdgcn_cvt_pk_fp8_f32(ev[10], ev[11], u2, true);
                u3 = __builtin_amdgcn_cvt_pk_fp8_f32(ev[12], ev[13], u3, false);
                u3 = __builtin_amdgcn_cvt_pk_fp8_f32(ev[14], ev[15], u3, true);
                uint4 val;
                val.x = (unsigned)u0; val.y = (unsigned)u1;
                val.z = (unsigned)u2; val.w = (unsigned)u3;
                *(uint4*)(rowp + (size_t)h * 4 * 2048 * 2048) = val;
                if (h > 0) {
#pragma unroll
                    for (int e = 0; e < 16; ++e) {
                        float s = ev[e] * ev[e];
                        ev[e] = s * s;
                    }
                }
            }
        }
    } else if (blk < 2848) {
        // ---- pack_weights: 8 elements per thread ----
        int base = (blk - 2048) * 2048 + t * 8;
#pragma unroll
        for (int e = 0; e < 8; ++e) {
            int idx = base + e;
            float v;
            if (idx < 262144) {
                int l = idx >> 16, c = (idx >> 8) & 255, k = idx & 255;
                v = valW[((l * 4 + (c >> 6)) * 256 + k) * 64 + (c & 63)];
            } else if (idx < 524288) {
                int i2 = idx - 262144;
                int l = i2 >> 16, c = (i2 >> 8) & 255, k = i2 & 255;
                v = attnW[l * 65536 + k * 256 + c];
            } else if (idx < 1048576) {
                int i2 = idx - 524288;
                int l = i2 >> 17, c = (i2 >> 8) & 511, k = i2 & 255;
                v = ffnW1[l * 131072 + k * 512 + c];
            } else if (idx < 1572864) {
                int i2 = idx - 1048576;
                int l = i2 >> 17, c = (i2 >> 9) & 255, k = i2 & 511;
                v = ffnW2[l * 131072 + k * 256 + c];
            } else {
                int i2 = idx - 1572864;
                int c = i2 >> 8, k = i2 & 255;
                v = outW1[k * 256 + c];
            }
            wp[idx] = f2bf(v);
        }
    } else {
        // ---- input_mlp (8 rows per block) ----
        float (*xr)[IN_DIM_ + 2] = (float(*)[IN_DIM_ + 2])smem;
        int row0 = (blk - 2848) * 8;
        for (int idx = t; idx < 8 * IN_DIM_; idx += 256) {
            int r = idx / IN_DIM_, f = idx % IN_DIM_;
            int rr = row0 + r;
            float v;
            if (f < 3)       v = xc[rr * 3 + f];
            else if (f < 67) v = emb[rr * EMB_ + (f - 3)];
            else             v = lat[rr * 3 + (f - 67)];
            xr[r][f] = v;
        }
        __syncthreads();
        float acc[8] = {0.f, 0.f, 0.f, 0.f, 0.f, 0.f, 0.f, 0.f};
        for (int f = 0; f < IN_DIM_; ++f) {
            float w = W[f * HID_ + t];
#pragma unroll
            for (int r = 0; r < 8; ++r) acc[r] += xr[r][f] * w;
        }
        float bb = b[t];
#pragma unroll
        for (int r = 0; r < 8; ++r) {
            float v = fmaxf(acc[r] + bb, 0.f);
            feats[(row0 + r) * HID_ + t] = v;
            featsb[(row0 + r) * HID_ + t] = f2bf(v);
        }
    }
}

// ---------------------------------------------------------------------------
// pv_gemm v6 (R20): fp8 MFMA, 64-row blocks, grid 512, 2 blocks/CU,
// counted vmcnt 4/2/0.
// ---------------------------------------------------------------------------
__global__ __launch_bounds__(256, 2) void pv_gemm(const uchar* __restrict__ E,
                                                  const uchar* __restrict__ Vt,
                                                  ushort* __restrict__ attb) {
    __shared__ __align__(16) char lds[32768];
    int t = threadIdx.x;
    int l = t & 63, w = t >> 6;
    int lr = l & 15, g = l >> 4;

    int f = blockIdx.x;                 // 512 blocks
    int xcd = f & 7, s = f >> 3;        // s 0..63
    int combo = xcd * 2 + (s >> 5);     // 0..15
    int ib = s & 31;                    // 32 i-tiles of 64 rows
    int b = combo & 3, h = combo >> 2;
    int i_base = ib * 64;
    int hc = h * 64;

    const uchar* Eb = E + (size_t)(h * 4 + b) * 2048 * 2048;
    const uchar* VtB = Vt + (size_t)(b * 256 + hc) * 2048;

    const uchar* srcA;
    {
        int row = t >> 2, p = t & 3;
        srcA = Eb + (size_t)(i_base + row) * 2048 + ((p ^ ((row >> 1) & 3)) << 4);
    }
    const uchar* srcV;
    {
        int col = t >> 2, p = t & 3;
        srcV = VtB + (size_t)col * 2048 + ((p ^ ((col >> 1) & 3)) << 4);
    }
    auto STAGE = [&](int c) {
        char* base = lds + (c & 3) * 8192;
        GLOAD_LDS16(srcA + c * 64, base + t * 16);
        GLOAD_LDS16(srcV + c * 64, base + 4096 + t * 16);
    };

    f32x4 acc[4] = {};
    f32x4 accd = {};
    const long ones8 = 0x3838383838383838L;   // 8 x fp8(1.0)

    int r0 = w * 16 + lr;

    auto COMPUTE = [&](int c) {
        const char* As = lds + (c & 3) * 8192;
        const char* Vs = As + 4096;
#pragma unroll
        for (int kk = 0; kk < 2; ++kk) {
            int off = kk * 32 + g * 8;
            long a0 = *(const long*)(As + r0 * 64 + (off ^ (((r0 >> 1) & 3) << 4)));
            accd = MFMA8(a0, ones8, accd);
#pragma unroll
            for (int n = 0; n < 4; ++n) {
                int col = n * 16 + lr;
                long bv = *(const long*)(Vs + col * 64 + (off ^ (((col >> 1) & 3) << 4)));
                acc[n] = MFMA8(a0, bv, acc[n]);
            }
        }
    };

    STAGE(0);
    STAGE(1);
    STAGE(2);

    for (int c = 0; c < 30; ++c) {
        asm volatile("s_waitcnt vmcnt(4)" ::: "memory");
        __builtin_amdgcn_s_barrier();
        __builtin_amdgcn_sched_barrier(0);
        if (c < 29) STAGE(c + 3);
        COMPUTE(c);
    }
    asm volatile("s_waitcnt vmcnt(2)" ::: "memory");
    __builtin_amdgcn_s_barrier();
    __builtin_amdgcn_sched_barrier(0);
    COMPUTE(30);
    asm volatile("s_waitcnt vmcnt(0)" ::: "memory");
    __builtin_amdgcn_s_barrier();
    __builtin_amdgcn_sched_barrier(0);
    COMPUTE(31);

#pragma unroll
    for (int r = 0; r < 4; ++r) {
        float invd = 1.f / (accd[r] + 1e-8f);
        int row = i_base + w * 16 + g * 4 + r;
        size_t rb = ((size_t)b * N_ + row) * 256 + hc + lr;
#pragma unroll
        for (int n = 0; n < 4; ++n)
            attb[rb + n * 16] = f2bf(acc[n][r] * invd);
    }
}

// ---------------------------------------------------------------------------
// gemmM: LDS-dbuf staged A+B, KD=256. MODE 3 (V-proj fp8 transposed out) /
// MODE 4 (final).
// ---------------------------------------------------------------------------
template <int MODE>
__global__ __launch_bounds__(256) void gemmM(const ushort* __restrict__ A,
                                             const ushort* __restrict__ Bt,
                                             const float* __restrict__ bias,
                                             const float* __restrict__ resid,
                                             const float* __restrict__ lng,
                                             uchar* __restrict__ outb,
                                             float* __restrict__ outf) {
    __shared__ __align__(16) char lds[69632];
    int t = threadIdx.x;
    int l = t & 63, w = t >> 6;
    int lr = l & 15, g = l >> 4;
    int row0 = blockIdx.x * 16;
    f32x4 acc[4] = {};

    const ushort* srcA = A + (size_t)(row0 + (t >> 3)) * 256 + (((t & 7) ^ ((t >> 3) & 7)) << 3);
    const ushort* srcB[8];
#pragma unroll
    for (int q = 0; q < 8; ++q) {
        int cl = q * 32 + (t >> 3);
        srcB[q] = Bt + (size_t)cl * 256 + (((t & 7) ^ (cl & 7)) << 3);
    }
    auto STAGE = [&](int buf) {
        if (t < 128) GLOAD_LDS16(srcA, lds + buf * 2048 + t * 16);
#pragma unroll
        for (int q = 0; q < 8; ++q)
            GLOAD_LDS16(srcB[q], lds + 4096 + buf * 32768 + q * 4096 + t * 16);
        srcA += 64;
#pragma unroll
        for (int q = 0; q < 8; ++q) srcB[q] += 64;
    };

    int sw_a = (lr & 7) << 4;
    int aoff = lr * 128;

    STAGE(0);
#pragma unroll
    for (int c = 0; c < 4; ++c) {
        __syncthreads();
        if (c + 1 < 4) STAGE((c + 1) & 1);
        const char* As = lds + (c & 1) * 2048;
        const char* Ws = lds + 4096 + (c & 1) * 32768;

        short8 a0 = *(const short8*)(As + aoff + ((g * 16) ^ sw_a));
        short8 a1 = *(const short8*)(As + aoff + ((64 + g * 16) ^ sw_a));
#pragma unroll
        for (int n = 0; n < 4; ++n) {
            int cc = w * 64 + n * 16 + lr;
            const char* cb = Ws + cc * 128;
            int sw = (cc & 7) << 4;
            short8 b0 = *(const short8*)(cb + ((g * 16) ^ sw));
            short8 b1 = *(const short8*)(cb + ((64 + g * 16) ^ sw));
            acc[n] = MFMA16(a0, b0, acc[n]);
            acc[n] = MFMA16(a1, b1, acc[n]);
        }
    }
    __syncthreads();

    if constexpr (MODE == 3) {
        uchar* Ts = (uchar*)(lds + 8192);   // [256][16] fp8
#pragma unroll
        for (int n = 0; n < 4; ++n) {
            int c = w * 64 + n * 16 + lr;
            float bi = bias[c];
            int u = 0;
            u = __builtin_amdgcn_cvt_pk_fp8_f32(acc[n][0] + bi, acc[n][1] + bi, u, false);
            u = __builtin_amdgcn_cvt_pk_fp8_f32(acc[n][2] + bi, acc[n][3] + bi, u, true);
            *(int*)(Ts + c * 16 + g * 4) = u;
        }
        __syncthreads();
        {
            int c = t;
            int b = row0 >> 11;
            int n0 = row0 & 2047;
            *(uint4*)(outb + ((size_t)(b * 256 + c)) * 2048 + n0) = *(uint4*)(Ts + c * 16);
        }
    } else {  // MODE 4
        const float* W2 = resid;    // [256][3]
        const float* b2 = lng;      // [3]
        ushort(*Ts)[264] = (ushort(*)[264])(lds + 8192);
#pragma unroll
        for (int n = 0; n < 4; ++n) {
            int c = w * 64 + n * 16 + lr;
            float bi = bias[c];
#pragma unroll
            for (int r = 0; r < 4; ++r)
                Ts[g * 4 + r][c] = f2bf(fmaxf(acc[n][r] + bi, 0.f));
        }
        __syncthreads();
        int row = t >> 4, sg = t & 15;
        float p0 = 0.f, p1 = 0.f, p2 = 0.f;
#pragma unroll
        for (int e = 0; e < 16; ++e) {
            float x = bf2f(Ts[row][sg * 16 + e]);
            const float* wr = &W2[(sg * 16 + e) * 3];
            p0 += x * wr[0];
            p1 += x * wr[1];
            p2 += x * wr[2];
        }
#pragma unroll
        for (int off = 1; off < 16; off <<= 1) {
            p0 += __shfl_xor(p0, off, 64);
            p1 += __shfl_xor(p1, off, 64);
            p2 += __shfl_xor(p2, off, 64);
        }
        if (sg == 0) {
            int gr = row0 + row;
            outf[gr * 3 + 0] = p0 + b2[0];
            outf[gr * 3 + 1] = p1 + b2[1];
            outf[gr * 3 + 2] = p2 + b2[2];
        }
    }
}

// ---------------------------------------------------------------------------
// gemm_layer v5 (R17/R19/R20): M-tile 32, 512 threads; counted-vmcnt
// pipeline. P3 writes V(l+1) as fp8 transposed.
// ---------------------------------------------------------------------------
__global__ __launch_bounds__(512) void gemm_layer(
        const ushort* __restrict__ attb,
        const ushort* __restrict__ Wat, const float* __restrict__ pb,
        float* __restrict__ feats,
        const float* __restrict__ ln1g, const float* __restrict__ ln1b,
        const ushort* __restrict__ W1t, const float* __restrict__ b1,
        const ushort* __restrict__ W2t, const float* __restrict__ b2,
        const float* __restrict__ ln2g, const float* __restrict__ ln2b,
        ushort* __restrict__ featsb,
        const ushort* __restrict__ WvN, const float* __restrict__ vbN,
        uchar* __restrict__ Vt) {
    __shared__ __align__(16) char lds[122880];
    char* Aa = lds;              // 8KB (2x4KB); red overlay after P0
    char* Asp = lds + 8192;      // 16KB: x1 / x2 bf16 (32 rows x 512B)
    char* Wsp = lds + 24576;     // 2 x 32KB
    char* hidp = lds + 90112;    // 32KB (32 rows x 1024B); Ts overlay in P3

    int t = threadIdx.x;
    int l = t & 63, w = t >> 6;
    int cg = w & 3, mh = w >> 2;
    int lr = l & 15, g = l >> 4;
    int row0 = blockIdx.x * 32;
    int arow = mh * 16 + lr;
    int sw_a = (lr & 7) << 4;
    int trow = t >> 3, slot = t & 7;

    uint4 wA0, wA1, wA2, wA3;   // set A  <-> Wsp buf 0
    uint4 wB0, wB1, wB2, wB3;   // set B  <-> Wsp buf 1
    auto WLOADA = [&](const ushort* Wb, int stride, int colbase, int c) {
        const ushort* base = Wb + c * 64;
#pragma unroll
        for (int q = 0; q < 4; ++q) {
            int cl = colbase + q * 64 + trow;
            uint4 v = *(const uint4*)(base + (size_t)cl * stride + ((slot ^ (cl & 7)) << 3));
            if (q == 0) wA0 = v; else if (q == 1) wA1 = v;
            else if (q == 2) wA2 = v; else wA3 = v;
        }
    };
    auto WLOADB = [&](const ushort* Wb, int stride, int colbase, int c) {
        const ushort* base = Wb + c * 64;
#pragma unroll
        for (int q = 0; q < 4; ++q) {
            int cl = colbase + q * 64 + trow;
            uint4 v = *(const uint4*)(base + (size_t)cl * stride + ((slot ^ (cl & 7)) << 3));
            if (q == 0) wB0 = v; else if (q == 1) wB1 = v;
            else if (q == 2) wB2 = v; else wB3 = v;
        }
    };
    auto WSTOREA = [&]() {
        *(uint4*)(Wsp + 0 * 8192 + t * 16) = wA0;
        *(uint4*)(Wsp + 1 * 8192 + t * 16) = wA1;
        *(uint4*)(Wsp + 2 * 8192 + t * 16) = wA2;
        *(uint4*)(Wsp + 3 * 8192 + t * 16) = wA3;
    };
    auto WSTOREB = [&]() {
        char* base = Wsp + 32768;
        *(uint4*)(base + 0 * 8192 + t * 16) = wB0;
        *(uint4*)(base + 1 * 8192 + t * 16) = wB1;
        *(uint4*)(base + 2 * 8192 + t * 16) = wB2;
        *(uint4*)(base + 3 * 8192 + t * 16) = wB3;
    };

    // ---- P0: attn-proj (KD=256), 2-barrier form, Wsp buf0, set A ----
    const ushort* srcA = attb + (size_t)(row0 + trow) * 256 + ((slot ^ (trow & 7)) << 3);
    auto STAGEA = [&](int buf, int c) {
        if (t < 256) GLOAD_LDS16(srcA + c * 64, Aa + buf * 4096 + t * 16);
    };

    f32x4 acc0[4] = {};
    STAGEA(0, 0);
    WLOADA(Wat, 256, 0, 0);
#pragma unroll
    for (int c = 0; c < 4; ++c) {
        __syncthreads();
        WSTOREA();
        __syncthreads();
        if (c < 3) { WLOADA(Wat, 256, 0, c + 1); STAGEA((c + 1) & 1, c + 1); }
        else WLOADA(W1t, 256, 0, 0);       // W(0) of the P1/P2 pipeline

        const char* As = Aa + (c & 1) * 4096;
        short8 a0 = *(const short8*)(As + arow * 128 + ((g * 16) ^ sw_a));
        short8 a1 = *(const short8*)(As + arow * 128 + ((64 + g * 16) ^ sw_a));
#pragma unroll
        for (int n = 0; n < 4; ++n) {
            int cc = cg * 64 + n * 16 + lr;
            const char* cb = Wsp + cc * 128;
            int sw = (cc & 7) << 4;
            short8 b0 = *(const short8*)(cb + ((g * 16) ^ sw));
            short8 b1 = *(const short8*)(cb + ((64 + g * 16) ^ sw));
            acc0[n] = MFMA16(a0, b0, acc0[n]);
            acc0[n] = MFMA16(a1, b1, acc0[n]);
        }
    }
    __syncthreads();

    // ---- LN1 (x1 in regs; bf16 -> Asp) ----
    float* red1 = (float*)lds;          // [32][4]
    float* red2 = (float*)(lds + 512);
    float x1v[4][4];
    {
        float s1[4] = {0.f, 0.f, 0.f, 0.f}, s2[4] = {0.f, 0.f, 0.f, 0.f};
#pragma unroll
        for (int n = 0; n < 4; ++n) {
            int c = cg * 64 + n * 16 + lr;
            float bi = pb[c];
#pragma unroll
            for (int r = 0; r < 4; ++r) {
                int row = row0 + mh * 16 + g * 4 + r;
                float v = acc0[n][r] + bi + feats[(size_t)row * 256 + c];
                x1v[n][r] = v;
                s1[r] += v;
                s2[r] += v * v;
            }
        }
#pragma unroll
        for (int off = 1; off < 16; off <<= 1) {
#pragma unroll
            for (int r = 0; r < 4; ++r) {
                s1[r] += __shfl_xor(s1[r], off, 64);
                s2[r] += __shfl_xor(s2[r], off, 64);
            }
        }
        if (lr == 0) {
#pragma unroll
            for (int r = 0; r < 4; ++r) {
                red1[(mh * 16 + g * 4 + r) * 4 + cg] = s1[r];
                red2[(mh * 16 + g * 4 + r) * 4 + cg] = s2[r];
            }
        }
        __syncthreads();
#pragma unroll
        for (int n = 0; n < 4; ++n) {
            int c = cg * 64 + n * 16 + lr;
            float gg = ln1g[c], bb = ln1b[c];
#pragma unroll
            for (int r = 0; r < 4; ++r) {
                int rr = mh * 16 + g * 4 + r;
                float m1 = red1[rr * 4] + red1[rr * 4 + 1] + red1[rr * 4 + 2] + red1[rr * 4 + 3];
                float m2 = red2[rr * 4] + red2[rr * 4 + 1] + red2[rr * 4 + 2] + red2[rr * 4 + 3];
                float mu = m1 * (1.f / 256.f);
                float var = m2 * (1.f / 256.f) - mu * mu;
                float rstd = rsqrtf(var + 1e-5f);
                float o = (x1v[n][r] - mu) * rstd * gg + bb;
                x1v[n][r] = o;
                *(ushort*)(Asp + rr * 512 + ((2 * c) ^ ((rr & 7) << 4))) = f2bf(o);
            }
        }
    }

    // ---- P1+P2 pipeline prologue: Wsp[0]=W(0); issue W(1)->set B ----
    WSTOREA();
    WLOADB(W1t, 256, 0, 1);
    asm volatile("s_waitcnt lgkmcnt(0)" ::: "memory");
    __builtin_amdgcn_sched_barrier(0);
    __builtin_amdgcn_s_barrier();

    f32x4 acc1[4] = {}, acc1b[4] = {}, acc2[4] = {};
#pragma unroll
    for (int u = 0; u < 16; ++u) {
        const char* WB = Wsp + (u & 1) * 32768;
        short8 a0, a1;
        if (u < 8) {
            int c = u & 3;
            a0 = *(const short8*)(Asp + arow * 512 + ((c * 128 + g * 16) ^ sw_a));
            a1 = *(const short8*)(Asp + arow * 512 + ((c * 128 + 64 + g * 16) ^ sw_a));
        } else {
            int c = u - 8;
            a0 = *(const short8*)(hidp + arow * 1024 + ((c * 128 + g * 16) ^ sw_a));
            a1 = *(const short8*)(hidp + arow * 1024 + ((c * 128 + 64 + g * 16) ^ sw_a));
        }
#pragma unroll
        for (int n = 0; n < 4; ++n) {
            int cc = cg * 64 + n * 16 + lr;
            const char* cb = WB + cc * 128;
            int sw = (cc & 7) << 4;
            short8 b0 = *(const short8*)(cb + ((g * 16) ^ sw));
            short8 b1 = *(const short8*)(cb + ((64 + g * 16) ^ sw));
            if (u < 4)      { acc1[n] = MFMA16(a0, b0, acc1[n]);  acc1[n] = MFMA16(a1, b1, acc1[n]); }
            else if (u < 8) { acc1b[n] = MFMA16(a0, b0, acc1b[n]); acc1b[n] = MFMA16(a1, b1, acc1b[n]); }
            else            { acc2[n] = MFMA16(a0, b0, acc2[n]);  acc2[n] = MFMA16(a1, b1, acc2[n]); }
        }
        if (u == 3) {
#pragma unroll
            for (int n = 0; n < 4; ++n) {
                int cf = cg * 64 + n * 16 + lr;
                float bi = b1[cf];
#pragma unroll
                for (int r = 0; r < 4; ++r) {
                    int rw = mh * 16 + g * 4 + r;
                    float v = fmaxf(acc1[n][r] + bi, 0.f);
                    *(ushort*)(hidp + rw * 1024 + ((cf * 2) ^ ((rw & 7) << 4))) = f2bf(v);
                }
            }
        }
        if (u == 7) {
#pragma unroll
            for (int n = 0; n < 4; ++n) {
                int cf = 256 + cg * 64 + n * 16 + lr;
                float bi = b1[cf];
#pragma unroll
                for (int r = 0; r < 4; ++r) {
                    int rw = mh * 16 + g * 4 + r;
                    float v = fmaxf(acc1b[n][r] + bi, 0.f);
                    *(ushort*)(hidp + rw * 1024 + ((cf * 2) ^ ((rw & 7) << 4))) = f2bf(v);
                }
            }
        }
        // tail: issue W(u+2); wait W(u+1); store into buf[(u+1)&1]
        {
            int k = u + 2;
            bool issued = true;
            if (k < 4)       { if (u & 1) WLOADB(W1t, 256, 0, k);       else WLOADA(W1t, 256, 0, k); }
            else if (k < 8)  { if (u & 1) WLOADB(W1t, 256, 256, k - 4); else WLOADA(W1t, 256, 256, k - 4); }
            else if (k < 16) { if (u & 1) WLOADB(W2t, 512, 0, k - 8);   else WLOADA(W2t, 512, 0, k - 8); }
            else if (WvN)    { if (u & 1) WLOADB(WvN, 256, 0, k - 16);  else WLOADA(WvN, 256, 0, k - 16); }
            else issued = false;
            if (issued) asm volatile("s_waitcnt vmcnt(4)" ::: "memory");
            else        asm volatile("s_waitcnt vmcnt(0)" ::: "memory");
            __builtin_amdgcn_sched_barrier(0);
            if (u < 15 || WvN) { if ((u + 1) & 1) WSTOREB(); else WSTOREA(); }
            asm volatile("s_waitcnt lgkmcnt(0)" ::: "memory");
            __builtin_amdgcn_sched_barrier(0);
            __builtin_amdgcn_s_barrier();
        }
    }

    // ---- LN2 (resid = x1 regs) -> feats fp32+bf16; x2 -> Asp ----
#pragma unroll
    for (int n = 0; n < 4; ++n) {
        int c = cg * 64 + n * 16 + lr;
        float bi = b2[c];
#pragma unroll
        for (int r = 0; r < 4; ++r)
            acc2[n][r] = acc2[n][r] + bi + x1v[n][r];
    }
    {
        float* red1b = (float*)lds;
        float* red2b = (float*)(lds + 512);
        float s1[4] = {0.f, 0.f, 0.f, 0.f}, s2[4] = {0.f, 0.f, 0.f, 0.f};
#pragma unroll
        for (int n = 0; n < 4; ++n)
#pragma unroll
            for (int r = 0; r < 4; ++r) {
                s1[r] += acc2[n][r];
                s2[r] += acc2[n][r] * acc2[n][r];
            }
#pragma unroll
        for (int off = 1; off < 16; off <<= 1) {
#pragma unroll
            for (int r = 0; r < 4; ++r) {
                s1[r] += __shfl_xor(s1[r], off, 64);
                s2[r] += __shfl_xor(s2[r], off, 64);
            }
        }
        if (lr == 0) {
#pragma unroll
            for (int r = 0; r < 4; ++r) {
                red1b[(mh * 16 + g * 4 + r) * 4 + cg] = s1[r];
                red2b[(mh * 16 + g * 4 + r) * 4 + cg] = s2[r];
            }
        }
        __syncthreads();
#pragma unroll
        for (int n = 0; n < 4; ++n) {
            int c = cg * 64 + n * 16 + lr;
            float gg = ln2g[c], bb = ln2b[c];
#pragma unroll
            for (int r = 0; r < 4; ++r) {
                int rr = mh * 16 + g * 4 + r;
                float m1 = red1b[rr * 4] + red1b[rr * 4 + 1] + red1b[rr * 4 + 2] + red1b[rr * 4 + 3];
                float m2 = red2b[rr * 4] + red2b[rr * 4 + 1] + red2b[rr * 4 + 2] + red2b[rr * 4 + 3];
                float mu = m1 * (1.f / 256.f);
                float var = m2 * (1.f / 256.f) - mu * mu;
                float rstd = rsqrtf(var + 1e-5f);
                int row = row0 + rr;
                float o = (acc2[n][r] - mu) * rstd * gg + bb;
                feats[(size_t)row * 256 + c] = o;
                ushort ob = f2bf(o);
                featsb[(size_t)row * 256 + c] = ob;
                *(ushort*)(Asp + rr * 512 + ((2 * c) ^ ((rr & 7) << 4))) = ob;
            }
        }
    }
    __syncthreads();

    // ---- P3: V(l+1) = x2 @ WvN, chunks 16..19; fp8 transposed out ----
    if (WvN) {
        f32x4 acc3[4] = {};
#pragma unroll
        for (int u3 = 0; u3 < 4; ++u3) {
            const char* WB = Wsp + (u3 & 1) * 32768;
            short8 a0 = *(const short8*)(Asp + arow * 512 + ((u3 * 128 + g * 16) ^ sw_a));
            short8 a1 = *(const short8*)(Asp + arow * 512 + ((u3 * 128 + 64 + g * 16) ^ sw_a));
#pragma unroll
            for (int n = 0; n < 4; ++n) {
                int cc = cg * 64 + n * 16 + lr;
                const char* cb = WB + cc * 128;
                int sw = (cc & 7) << 4;
                short8 b0 = *(const short8*)(cb + ((g * 16) ^ sw));
                short8 b1 = *(const short8*)(cb + ((64 + g * 16) ^ sw));
                acc3[n] = MFMA16(a0, b0, acc3[n]);
                acc3[n] = MFMA16(a1, b1, acc3[n]);
            }
            if (u3 < 3) {
                if (u3 < 2) {
                    if (u3 & 1) WLOADB(WvN, 256, 0, u3 + 2);
                    else        WLOADA(WvN, 256, 0, u3 + 2);
                    asm volatile("s_waitcnt vmcnt(4)" ::: "memory");
                } else {
                    asm volatile("s_waitcnt vmcnt(0)" ::: "memory");
                }
                __builtin_amdgcn_sched_barrier(0);
                if ((u3 + 1) & 1) WSTOREB(); else WSTOREA();
                asm volatile("s_waitcnt lgkmcnt(0)" ::: "memory");
                __builtin_amdgcn_sched_barrier(0);
                __builtin_amdgcn_s_barrier();
            }
        }
        __syncthreads();
        uchar* Ts = (uchar*)hidp;   // [256][32] fp8 = 8KB
#pragma unroll
        for (int n = 0; n < 4; ++n) {
            int c = cg * 64 + n * 16 + lr;
            float bi = vbN[c];
            int u = 0;
            u = __builtin_amdgcn_cvt_pk_fp8_f32(acc3[n][0] + bi, acc3[n][1] + bi, u, false);
            u = __builtin_amdgcn_cvt_pk_fp8_f32(acc3[n][2] + bi, acc3[n][3] + bi, u, true);
            *(int*)(Ts + c * 32 + mh * 16 + g * 4) = u;
        }
        __syncthreads();
        if (t < 256) {
            int c = t;
            int b = row0 >> 11;
            int n0 = row0 & 2047;
            uchar* dst = Vt + ((size_t)(b * 256 + c)) * 2048 + n0;
            *(uint4*)dst = *(uint4*)(Ts + c * 32);
            *(uint4*)(dst + 16) = *(uint4*)(Ts + c * 32 + 16);
        }
    }
}

// ---------------------------------------------------------------------------
extern "C" void kernel_launch(void* const* d_in, const int* in_sizes, int n_in,
                              void* d_out, int out_size, void* d_ws, size_t ws_size,
                              hipStream_t stream) {
    const float* lat    = (const float*)d_in[0];
    const float* xc     = (const float*)d_in[1];
    const float* emb    = (const float*)d_in[2];
    const float* in_W   = (const float*)d_in[3];
    const float* in_b   = (const float*)d_in[4];
    const float* val_W  = (const float*)d_in[5];
    const float* val_b  = (const float*)d_in[6];
    const float* attn_W = (const float*)d_in[7];
    const float* attn_b = (const float*)d_in[8];
    const float* ln1_g  = (const float*)d_in[9];
    const float* ln1_b  = (const float*)d_in[10];
    const float* ln2_g  = (const float*)d_in[11];
    const float* ln2_b  = (const float*)d_in[12];
    const float* ffn_W1 = (const float*)d_in[13];
    const float* ffn_b1 = (const float*)d_in[14];
    const float* ffn_W2 = (const float*)d_in[15];
    const float* ffn_b2 = (const float*)d_in[16];
    const float* out_W1 = (const float*)d_in[17];
    const float* out_b1 = (const float*)d_in[18];
    const float* out_W2 = (const float*)d_in[19];
    const float* out_b2 = (const float*)d_in[20];

    char* W = (char*)d_ws;
    float*  feats  = (float*)W;                                // 8 MB
    ushort* featsb = (ushort*)(W + (8u << 20));                // 4 MB
    ushort* attb   = (ushort*)(W + (12u << 20));               // 4 MB
    uchar*  Vt8    = (uchar*)(W + (16u << 20));                // 2 MB fp8
    ushort* wp     = (ushort*)(W + (20u << 20));               // 3.2 MB
    uchar*  E8     = (uchar*)(W + (24u << 20));                // 64 MiB fp8
    ushort* Wvt  = wp;
    ushort* Wat  = wp + 262144;
    ushort* W1t  = wp + 524288;
    ushort* W2t  = wp + 1048576;
    ushort* Wo1t = wp + 1572864;

    setup_all4<<<3872, 256, 0, stream>>>(
        val_W, attn_W, ffn_W1, ffn_W2, out_W1, wp,
        xc, emb, lat, in_W, in_b, feats, featsb, E8);

    gemmM<3><<<R_ / 16, 256, 0, stream>>>(
        featsb, Wvt, val_b, nullptr, nullptr, Vt8, nullptr);

    for (int l = 0; l < LAYERS_; ++l) {
        pv_gemm<<<512, 256, 0, stream>>>(E8, Vt8, attb);
        const ushort* WvN = (l + 1 < LAYERS_) ? (Wvt + (l + 1) * 65536) : nullptr;
        const float* vbN = val_b + ((l + 1 < LAYERS_) ? (l + 1) * 256 : 0);
        gemm_layer<<<R_ / 32, 512, 0, stream>>>(
            attb, Wat + l * 65536, attn_b + l * 256,
            feats, ln1_g + l * 256, ln1_b + l * 256,
            W1t + l * 131072, ffn_b1 + l * 512,
            W2t + l * 131072, ffn_b2 + l * 256,
            ln2_g + l * 256, ln2_b + l * 256,
            featsb, WvN, vbN, Vt8);
    }

    gemmM<4><<<R_ / 16, 256, 0, stream>>>(
        featsb, Wo1t, out_b1, out_W2, out_b2, nullptr, (float*)d_out);
}

// Round 25
// 200.466 us; speedup vs baseline: 1.0102x; 1.0102x over previous
//
#include <hip/hip_runtime.h>

#define B_ 4
#define N_ 2048
#define R_ (B_ * N_)      // 8192 rows
#define HID_ 256
#define EMB_ 64
#define IN_DIM_ 70
#define H_ 4
#define HEAD_ 64
#define FFN_ 512
#define LAYERS_ 4

typedef __attribute__((ext_vector_type(8))) short short8;
typedef __attribute__((ext_vector_type(4))) float f32x4;
typedef unsigned short ushort;
typedef unsigned char uchar;

static __device__ __forceinline__ ushort f2bf(float f) {
    unsigned u = __builtin_bit_cast(unsigned, f);
    u += 0x7fffu + ((u >> 16) & 1u);   // RNE
    return (ushort)(u >> 16);
}
static __device__ __forceinline__ float bf2f(ushort u) {
    unsigned x = ((unsigned)u) << 16;
    return __builtin_bit_cast(float, x);
}

#define GLOAD_LDS16(g, l)                                              \
    __builtin_amdgcn_global_load_lds(                                  \
        (const __attribute__((address_space(1))) void*)(g),            \
        (__attribute__((address_space(3))) void*)(l), 16, 0, 0)

#define MFMA16(a, b, c) __builtin_amdgcn_mfma_f32_16x16x32_bf16(a, b, c, 0, 0, 0)
#define MFMA8(a, b, c) __builtin_amdgcn_mfma_f32_16x16x32_fp8_fp8(a, b, c, 0, 0, 0)

// ---------------------------------------------------------------------------
// setup_all5: fused ebuild (blocks 0..2047, long pole first) + pack_weights
// (2048..2847) + input_mlp (2848..3871).
// ebuild: R23 layout (32i x 256j, lane=t&31 owns 8 j, uint2 stores) + the
// R24-verified exp2 ladder: E3 = exp2(d2*ch3) once, E2=E3^4, E1=E2^4,
// E0=E1^4 (2 full-rate squarings per step). exp2/thread 128 -> 32.
// ---------------------------------------------------------------------------
__global__ __launch_bounds__(256) void setup_all5(
        const float* __restrict__ valW, const float* __restrict__ attnW,
        const float* __restrict__ ffnW1, const float* __restrict__ ffnW2,
        const float* __restrict__ outW1, ushort* __restrict__ wp,
        const float* __restrict__ xc, const float* __restrict__ emb,
        const float* __restrict__ lat, const float* __restrict__ W,
        const float* __restrict__ b, float* __restrict__ feats,
        ushort* __restrict__ featsb, uchar* __restrict__ E) {
    __shared__ __align__(16) char smem[9216];
    int blk = blockIdx.x;
    int t = threadIdx.x;

    if (blk < 2048) {
        // ---- ebuild (fp8 E): 32 i x 256 j per block ----
        float4* civ = (float4*)smem;             // 32
        float4* cjv = (float4*)(smem + 512);     // 256
        int f = blk;
        int jb = f & 7, ibl = (f >> 3) & 63, bb2 = f >> 9;
        const float* xb = xc + (size_t)bb2 * N_ * 3;
        if (t < 32) {
            const float* p = &xb[(ibl * 32 + t) * 3];
            float x = p[0], y = p[1], z = p[2];
            civ[t] = make_float4(x, y, z, x * x + y * y + z * z);
        }
        {
            const float* p = &xb[(jb * 256 + t) * 3];
            float x = p[0], y = p[1], z = p[2];
            cjv[t] = make_float4(x, y, z, x * x + y * y + z * z);
        }
        __syncthreads();
        int lane = t & 31, ig = t >> 5;          // lane: 8 j; ig: 4 i
        float4 cj[8];
#pragma unroll
        for (int e = 0; e < 8; ++e) cj[e] = cjv[lane * 8 + e];
        const float ch3 = -0.0625f * 1.44269504088896f;   // h=3: inv=1/16
        uchar* Ebase = E + ((size_t)bb2 * 2048 + ibl * 32) * 2048 + (size_t)jb * 256 + lane * 8;

        for (int r = 0; r < 4; ++r) {
            int i = ig * 4 + r;
            float4 ci = civ[i];
            float ev[8];
#pragma unroll
            for (int e = 0; e < 8; ++e) {
                float d = (ci.w + cj[e].w) -
                          2.f * (ci.x * cj[e].x + ci.y * cj[e].y + ci.z * cj[e].z);
                ev[e] = exp2f(d * ch3);
            }
            uchar* rowp = Ebase + (size_t)i * 2048;
            // store h=3, then power down: E_{h-1} = E_h^4
#pragma unroll
            for (int h = 3; h >= 0; --h) {
                int lo = 0, hi = 0;
                lo = __builtin_amdgcn_cvt_pk_fp8_f32(ev[0], ev[1], lo, false);
                lo = __builtin_amdgcn_cvt_pk_fp8_f32(ev[2], ev[3], lo, true);
                hi = __builtin_amdgcn_cvt_pk_fp8_f32(ev[4], ev[5], hi, false);
                hi = __builtin_amdgcn_cvt_pk_fp8_f32(ev[6], ev[7], hi, true);
                uint2 val;
                val.x = (unsigned)lo;
                val.y = (unsigned)hi;
                *(uint2*)(rowp + (size_t)h * 4 * 2048 * 2048) = val;
                if (h > 0) {
#pragma unroll
                    for (int e = 0; e < 8; ++e) {
                        float s = ev[e] * ev[e];
                        ev[e] = s * s;
                    }
                }
            }
        }
    } else if (blk < 2848) {
        // ---- pack_weights: 8 elements per thread ----
        int base = (blk - 2048) * 2048 + t * 8;
#pragma unroll
        for (int e = 0; e < 8; ++e) {
            int idx = base + e;
            float v;
            if (idx < 262144) {
                int l = idx >> 16, c = (idx >> 8) & 255, k = idx & 255;
                v = valW[((l * 4 + (c >> 6)) * 256 + k) * 64 + (c & 63)];
            } else if (idx < 524288) {
                int i2 = idx - 262144;
                int l = i2 >> 16, c = (i2 >> 8) & 255, k = i2 & 255;
                v = attnW[l * 65536 + k * 256 + c];
            } else if (idx < 1048576) {
                int i2 = idx - 524288;
                int l = i2 >> 17, c = (i2 >> 8) & 511, k = i2 & 255;
                v = ffnW1[l * 131072 + k * 512 + c];
            } else if (idx < 1572864) {
                int i2 = idx - 1048576;
                int l = i2 >> 17, c = (i2 >> 9) & 255, k = i2 & 511;
                v = ffnW2[l * 131072 + k * 256 + c];
            } else {
                int i2 = idx - 1572864;
                int c = i2 >> 8, k = i2 & 255;
                v = outW1[k * 256 + c];
            }
            wp[idx] = f2bf(v);
        }
    } else {
        // ---- input_mlp (8 rows per block) ----
        float (*xr)[IN_DIM_ + 2] = (float(*)[IN_DIM_ + 2])smem;
        int row0 = (blk - 2848) * 8;
        for (int idx = t; idx < 8 * IN_DIM_; idx += 256) {
            int r = idx / IN_DIM_, f = idx % IN_DIM_;
            int rr = row0 + r;
            float v;
            if (f < 3)       v = xc[rr * 3 + f];
            else if (f < 67) v = emb[rr * EMB_ + (f - 3)];
            else             v = lat[rr * 3 + (f - 67)];
            xr[r][f] = v;
        }
        __syncthreads();
        float acc[8] = {0.f, 0.f, 0.f, 0.f, 0.f, 0.f, 0.f, 0.f};
        for (int f = 0; f < IN_DIM_; ++f) {
            float w = W[f * HID_ + t];
#pragma unroll
            for (int r = 0; r < 8; ++r) acc[r] += xr[r][f] * w;
        }
        float bb = b[t];
#pragma unroll
        for (int r = 0; r < 8; ++r) {
            float v = fmaxf(acc[r] + bb, 0.f);
            feats[(row0 + r) * HID_ + t] = v;
            featsb[(row0 + r) * HID_ + t] = f2bf(v);
        }
    }
}

// ---------------------------------------------------------------------------
// pv_gemm v6 (R20): fp8 MFMA, 64-row blocks, grid 512, 2 blocks/CU,
// counted vmcnt 4/2/0.
// ---------------------------------------------------------------------------
__global__ __launch_bounds__(256, 2) void pv_gemm(const uchar* __restrict__ E,
                                                  const uchar* __restrict__ Vt,
                                                  ushort* __restrict__ attb) {
    __shared__ __align__(16) char lds[32768];
    int t = threadIdx.x;
    int l = t & 63, w = t >> 6;
    int lr = l & 15, g = l >> 4;

    int f = blockIdx.x;                 // 512 blocks
    int xcd = f & 7, s = f >> 3;        // s 0..63
    int combo = xcd * 2 + (s >> 5);     // 0..15
    int ib = s & 31;                    // 32 i-tiles of 64 rows
    int b = combo & 3, h = combo >> 2;
    int i_base = ib * 64;
    int hc = h * 64;

    const uchar* Eb = E + (size_t)(h * 4 + b) * 2048 * 2048;
    const uchar* VtB = Vt + (size_t)(b * 256 + hc) * 2048;

    const uchar* srcA;
    {
        int row = t >> 2, p = t & 3;
        srcA = Eb + (size_t)(i_base + row) * 2048 + ((p ^ ((row >> 1) & 3)) << 4);
    }
    const uchar* srcV;
    {
        int col = t >> 2, p = t & 3;
        srcV = VtB + (size_t)col * 2048 + ((p ^ ((col >> 1) & 3)) << 4);
    }
    auto STAGE = [&](int c) {
        char* base = lds + (c & 3) * 8192;
        GLOAD_LDS16(srcA + c * 64, base + t * 16);
        GLOAD_LDS16(srcV + c * 64, base + 4096 + t * 16);
    };

    f32x4 acc[4] = {};
    f32x4 accd = {};
    const long ones8 = 0x3838383838383838L;   // 8 x fp8(1.0)

    int r0 = w * 16 + lr;

    auto COMPUTE = [&](int c) {
        const char* As = lds + (c & 3) * 8192;
        const char* Vs = As + 4096;
#pragma unroll
        for (int kk = 0; kk < 2; ++kk) {
            int off = kk * 32 + g * 8;
            long a0 = *(const long*)(As + r0 * 64 + (off ^ (((r0 >> 1) & 3) << 4)));
            accd = MFMA8(a0, ones8, accd);
#pragma unroll
            for (int n = 0; n < 4; ++n) {
                int col = n * 16 + lr;
                long bv = *(const long*)(Vs + col * 64 + (off ^ (((col >> 1) & 3) << 4)));
                acc[n] = MFMA8(a0, bv, acc[n]);
            }
        }
    };

    STAGE(0);
    STAGE(1);
    STAGE(2);

    for (int c = 0; c < 30; ++c) {
        asm volatile("s_waitcnt vmcnt(4)" ::: "memory");
        __builtin_amdgcn_s_barrier();
        __builtin_amdgcn_sched_barrier(0);
        if (c < 29) STAGE(c + 3);
        COMPUTE(c);
    }
    asm volatile("s_waitcnt vmcnt(2)" ::: "memory");
    __builtin_amdgcn_s_barrier();
    __builtin_amdgcn_sched_barrier(0);
    COMPUTE(30);
    asm volatile("s_waitcnt vmcnt(0)" ::: "memory");
    __builtin_amdgcn_s_barrier();
    __builtin_amdgcn_sched_barrier(0);
    COMPUTE(31);

#pragma unroll
    for (int r = 0; r < 4; ++r) {
        float invd = 1.f / (accd[r] + 1e-8f);
        int row = i_base + w * 16 + g * 4 + r;
        size_t rb = ((size_t)b * N_ + row) * 256 + hc + lr;
#pragma unroll
        for (int n = 0; n < 4; ++n)
            attb[rb + n * 16] = f2bf(acc[n][r] * invd);
    }
}

// ---------------------------------------------------------------------------
// gemmM: LDS-dbuf staged A+B, KD=256. MODE 3 (V-proj fp8 transposed out) /
// MODE 4 (final).
// ---------------------------------------------------------------------------
template <int MODE>
__global__ __launch_bounds__(256) void gemmM(const ushort* __restrict__ A,
                                             const ushort* __restrict__ Bt,
                                             const float* __restrict__ bias,
                                             const float* __restrict__ resid,
                                             const float* __restrict__ lng,
                                             uchar* __restrict__ outb,
                                             float* __restrict__ outf) {
    __shared__ __align__(16) char lds[69632];
    int t = threadIdx.x;
    int l = t & 63, w = t >> 6;
    int lr = l & 15, g = l >> 4;
    int row0 = blockIdx.x * 16;
    f32x4 acc[4] = {};

    const ushort* srcA = A + (size_t)(row0 + (t >> 3)) * 256 + (((t & 7) ^ ((t >> 3) & 7)) << 3);
    const ushort* srcB[8];
#pragma unroll
    for (int q = 0; q < 8; ++q) {
        int cl = q * 32 + (t >> 3);
        srcB[q] = Bt + (size_t)cl * 256 + (((t & 7) ^ (cl & 7)) << 3);
    }
    auto STAGE = [&](int buf) {
        if (t < 128) GLOAD_LDS16(srcA, lds + buf * 2048 + t * 16);
#pragma unroll
        for (int q = 0; q < 8; ++q)
            GLOAD_LDS16(srcB[q], lds + 4096 + buf * 32768 + q * 4096 + t * 16);
        srcA += 64;
#pragma unroll
        for (int q = 0; q < 8; ++q) srcB[q] += 64;
    };

    int sw_a = (lr & 7) << 4;
    int aoff = lr * 128;

    STAGE(0);
#pragma unroll
    for (int c = 0; c < 4; ++c) {
        __syncthreads();
        if (c + 1 < 4) STAGE((c + 1) & 1);
        const char* As = lds + (c & 1) * 2048;
        const char* Ws = lds + 4096 + (c & 1) * 32768;

        short8 a0 = *(const short8*)(As + aoff + ((g * 16) ^ sw_a));
        short8 a1 = *(const short8*)(As + aoff + ((64 + g * 16) ^ sw_a));
#pragma unroll
        for (int n = 0; n < 4; ++n) {
            int cc = w * 64 + n * 16 + lr;
            const char* cb = Ws + cc * 128;
            int sw = (cc & 7) << 4;
            short8 b0 = *(const short8*)(cb + ((g * 16) ^ sw));
            short8 b1 = *(const short8*)(cb + ((64 + g * 16) ^ sw));
            acc[n] = MFMA16(a0, b0, acc[n]);
            acc[n] = MFMA16(a1, b1, acc[n]);
        }
    }
    __syncthreads();

    if constexpr (MODE == 3) {
        uchar* Ts = (uchar*)(lds + 8192);   // [256][16] fp8
#pragma unroll
        for (int n = 0; n < 4; ++n) {
            int c = w * 64 + n * 16 + lr;
            float bi = bias[c];
            int u = 0;
            u = __builtin_amdgcn_cvt_pk_fp8_f32(acc[n][0] + bi, acc[n][1] + bi, u, false);
            u = __builtin_amdgcn_cvt_pk_fp8_f32(acc[n][2] + bi, acc[n][3] + bi, u, true);
            *(int*)(Ts + c * 16 + g * 4) = u;
        }
        __syncthreads();
        {
            int c = t;
            int b = row0 >> 11;
            int n0 = row0 & 2047;
            *(uint4*)(outb + ((size_t)(b * 256 + c)) * 2048 + n0) = *(uint4*)(Ts + c * 16);
        }
    } else {  // MODE 4
        const float* W2 = resid;    // [256][3]
        const float* b2 = lng;      // [3]
        ushort(*Ts)[264] = (ushort(*)[264])(lds + 8192);
#pragma unroll
        for (int n = 0; n < 4; ++n) {
            int c = w * 64 + n * 16 + lr;
            float bi = bias[c];
#pragma unroll
            for (int r = 0; r < 4; ++r)
                Ts[g * 4 + r][c] = f2bf(fmaxf(acc[n][r] + bi, 0.f));
        }
        __syncthreads();
        int row = t >> 4, sg = t & 15;
        float p0 = 0.f, p1 = 0.f, p2 = 0.f;
#pragma unroll
        for (int e = 0; e < 16; ++e) {
            float x = bf2f(Ts[row][sg * 16 + e]);
            const float* wr = &W2[(sg * 16 + e) * 3];
            p0 += x * wr[0];
            p1 += x * wr[1];
            p2 += x * wr[2];
        }
#pragma unroll
        for (int off = 1; off < 16; off <<= 1) {
            p0 += __shfl_xor(p0, off, 64);
            p1 += __shfl_xor(p1, off, 64);
            p2 += __shfl_xor(p2, off, 64);
        }
        if (sg == 0) {
            int gr = row0 + row;
            outf[gr * 3 + 0] = p0 + b2[0];
            outf[gr * 3 + 1] = p1 + b2[1];
            outf[gr * 3 + 2] = p2 + b2[2];
        }
    }
}

// ---------------------------------------------------------------------------
// gemm_layer v5 (R17/R19/R20): M-tile 32, 512 threads; counted-vmcnt
// pipeline. P3 writes V(l+1) as fp8 transposed.
// ---------------------------------------------------------------------------
__global__ __launch_bounds__(512) void gemm_layer(
        const ushort* __restrict__ attb,
        const ushort* __restrict__ Wat, const float* __restrict__ pb,
        float* __restrict__ feats,
        const float* __restrict__ ln1g, const float* __restrict__ ln1b,
        const ushort* __restrict__ W1t, const float* __restrict__ b1,
        const ushort* __restrict__ W2t, const float* __restrict__ b2,
        const float* __restrict__ ln2g, const float* __restrict__ ln2b,
        ushort* __restrict__ featsb,
        const ushort* __restrict__ WvN, const float* __restrict__ vbN,
        uchar* __restrict__ Vt) {
    __shared__ __align__(16) char lds[122880];
    char* Aa = lds;              // 8KB (2x4KB); red overlay after P0
    char* Asp = lds + 8192;      // 16KB: x1 / x2 bf16 (32 rows x 512B)
    char* Wsp = lds + 24576;     // 2 x 32KB
    char* hidp = lds + 90112;    // 32KB (32 rows x 1024B); Ts overlay in P3

    int t = threadIdx.x;
    int l = t & 63, w = t >> 6;
    int cg = w & 3, mh = w >> 2;
    int lr = l & 15, g = l >> 4;
    int row0 = blockIdx.x * 32;
    int arow = mh * 16 + lr;
    int sw_a = (lr & 7) << 4;
    int trow = t >> 3, slot = t & 7;

    uint4 wA0, wA1, wA2, wA3;   // set A  <-> Wsp buf 0
    uint4 wB0, wB1, wB2, wB3;   // set B  <-> Wsp buf 1
    auto WLOADA = [&](const ushort* Wb, int stride, int colbase, int c) {
        const ushort* base = Wb + c * 64;
#pragma unroll
        for (int q = 0; q < 4; ++q) {
            int cl = colbase + q * 64 + trow;
            uint4 v = *(const uint4*)(base + (size_t)cl * stride + ((slot ^ (cl & 7)) << 3));
            if (q == 0) wA0 = v; else if (q == 1) wA1 = v;
            else if (q == 2) wA2 = v; else wA3 = v;
        }
    };
    auto WLOADB = [&](const ushort* Wb, int stride, int colbase, int c) {
        const ushort* base = Wb + c * 64;
#pragma unroll
        for (int q = 0; q < 4; ++q) {
            int cl = colbase + q * 64 + trow;
            uint4 v = *(const uint4*)(base + (size_t)cl * stride + ((slot ^ (cl & 7)) << 3));
            if (q == 0) wB0 = v; else if (q == 1) wB1 = v;
            else if (q == 2) wB2 = v; else wB3 = v;
        }
    };
    auto WSTOREA = [&]() {
        *(uint4*)(Wsp + 0 * 8192 + t * 16) = wA0;
        *(uint4*)(Wsp + 1 * 8192 + t * 16) = wA1;
        *(uint4*)(Wsp + 2 * 8192 + t * 16) = wA2;
        *(uint4*)(Wsp + 3 * 8192 + t * 16) = wA3;
    };
    auto WSTOREB = [&]() {
        char* base = Wsp + 32768;
        *(uint4*)(base + 0 * 8192 + t * 16) = wB0;
        *(uint4*)(base + 1 * 8192 + t * 16) = wB1;
        *(uint4*)(base + 2 * 8192 + t * 16) = wB2;
        *(uint4*)(base + 3 * 8192 + t * 16) = wB3;
    };

    // ---- P0: attn-proj (KD=256), 2-barrier form, Wsp buf0, set A ----
    const ushort* srcA = attb + (size_t)(row0 + trow) * 256 + ((slot ^ (trow & 7)) << 3);
    auto STAGEA = [&](int buf, int c) {
        if (t < 256) GLOAD_LDS16(srcA + c * 64, Aa + buf * 4096 + t * 16);
    };

    f32x4 acc0[4] = {};
    STAGEA(0, 0);
    WLOADA(Wat, 256, 0, 0);
#pragma unroll
    for (int c = 0; c < 4; ++c) {
        __syncthreads();
        WSTOREA();
        __syncthreads();
        if (c < 3) { WLOADA(Wat, 256, 0, c + 1); STAGEA((c + 1) & 1, c + 1); }
        else WLOADA(W1t, 256, 0, 0);       // W(0) of the P1/P2 pipeline

        const char* As = Aa + (c & 1) * 4096;
        short8 a0 = *(const short8*)(As + arow * 128 + ((g * 16) ^ sw_a));
        short8 a1 = *(const short8*)(As + arow * 128 + ((64 + g * 16) ^ sw_a));
#pragma unroll
        for (int n = 0; n < 4; ++n) {
            int cc = cg * 64 + n * 16 + lr;
            const char* cb = Wsp + cc * 128;
            int sw = (cc & 7) << 4;
            short8 b0 = *(const short8*)(cb + ((g * 16) ^ sw));
            short8 b1 = *(const short8*)(cb + ((64 + g * 16) ^ sw));
            acc0[n] = MFMA16(a0, b0, acc0[n]);
            acc0[n] = MFMA16(a1, b1, acc0[n]);
        }
    }
    __syncthreads();

    // ---- LN1 (x1 in regs; bf16 -> Asp) ----
    float* red1 = (float*)lds;          // [32][4]
    float* red2 = (float*)(lds + 512);
    float x1v[4][4];
    {
        float s1[4] = {0.f, 0.f, 0.f, 0.f}, s2[4] = {0.f, 0.f, 0.f, 0.f};
#pragma unroll
        for (int n = 0; n < 4; ++n) {
            int c = cg * 64 + n * 16 + lr;
            float bi = pb[c];
#pragma unroll
            for (int r = 0; r < 4; ++r) {
                int row = row0 + mh * 16 + g * 4 + r;
                float v = acc0[n][r] + bi + feats[(size_t)row * 256 + c];
                x1v[n][r] = v;
                s1[r] += v;
                s2[r] += v * v;
            }
        }
#pragma unroll
        for (int off = 1; off < 16; off <<= 1) {
#pragma unroll
            for (int r = 0; r < 4; ++r) {
                s1[r] += __shfl_xor(s1[r], off, 64);
                s2[r] += __shfl_xor(s2[r], off, 64);
            }
        }
        if (lr == 0) {
#pragma unroll
            for (int r = 0; r < 4; ++r) {
                red1[(mh * 16 + g * 4 + r) * 4 + cg] = s1[r];
                red2[(mh * 16 + g * 4 + r) * 4 + cg] = s2[r];
            }
        }
        __syncthreads();
#pragma unroll
        for (int n = 0; n < 4; ++n) {
            int c = cg * 64 + n * 16 + lr;
            float gg = ln1g[c], bb = ln1b[c];
#pragma unroll
            for (int r = 0; r < 4; ++r) {
                int rr = mh * 16 + g * 4 + r;
                float m1 = red1[rr * 4] + red1[rr * 4 + 1] + red1[rr * 4 + 2] + red1[rr * 4 + 3];
                float m2 = red2[rr * 4] + red2[rr * 4 + 1] + red2[rr * 4 + 2] + red2[rr * 4 + 3];
                float mu = m1 * (1.f / 256.f);
                float var = m2 * (1.f / 256.f) - mu * mu;
                float rstd = rsqrtf(var + 1e-5f);
                float o = (x1v[n][r] - mu) * rstd * gg + bb;
                x1v[n][r] = o;
                *(ushort*)(Asp + rr * 512 + ((2 * c) ^ ((rr & 7) << 4))) = f2bf(o);
            }
        }
    }

    // ---- P1+P2 pipeline prologue: Wsp[0]=W(0); issue W(1)->set B ----
    WSTOREA();
    WLOADB(W1t, 256, 0, 1);
    asm volatile("s_waitcnt lgkmcnt(0)" ::: "memory");
    __builtin_amdgcn_sched_barrier(0);
    __builtin_amdgcn_s_barrier();

    f32x4 acc1[4] = {}, acc1b[4] = {}, acc2[4] = {};
#pragma unroll
    for (int u = 0; u < 16; ++u) {
        const char* WB = Wsp + (u & 1) * 32768;
        short8 a0, a1;
        if (u < 8) {
            int c = u & 3;
            a0 = *(const short8*)(Asp + arow * 512 + ((c * 128 + g * 16) ^ sw_a));
            a1 = *(const short8*)(Asp + arow * 512 + ((c * 128 + 64 + g * 16) ^ sw_a));
        } else {
            int c = u - 8;
            a0 = *(const short8*)(hidp + arow * 1024 + ((c * 128 + g * 16) ^ sw_a));
            a1 = *(const short8*)(hidp + arow * 1024 + ((c * 128 + 64 + g * 16) ^ sw_a));
        }
#pragma unroll
        for (int n = 0; n < 4; ++n) {
            int cc = cg * 64 + n * 16 + lr;
            const char* cb = WB + cc * 128;
            int sw = (cc & 7) << 4;
            short8 b0 = *(const short8*)(cb + ((g * 16) ^ sw));
            short8 b1 = *(const short8*)(cb + ((64 + g * 16) ^ sw));
            if (u < 4)      { acc1[n] = MFMA16(a0, b0, acc1[n]);  acc1[n] = MFMA16(a1, b1, acc1[n]); }
            else if (u < 8) { acc1b[n] = MFMA16(a0, b0, acc1b[n]); acc1b[n] = MFMA16(a1, b1, acc1b[n]); }
            else            { acc2[n] = MFMA16(a0, b0, acc2[n]);  acc2[n] = MFMA16(a1, b1, acc2[n]); }
        }
        if (u == 3) {
#pragma unroll
            for (int n = 0; n < 4; ++n) {
                int cf = cg * 64 + n * 16 + lr;
                float bi = b1[cf];
#pragma unroll
                for (int r = 0; r < 4; ++r) {
                    int rw = mh * 16 + g * 4 + r;
                    float v = fmaxf(acc1[n][r] + bi, 0.f);
                    *(ushort*)(hidp + rw * 1024 + ((cf * 2) ^ ((rw & 7) << 4))) = f2bf(v);
                }
            }
        }
        if (u == 7) {
#pragma unroll
            for (int n = 0; n < 4; ++n) {
                int cf = 256 + cg * 64 + n * 16 + lr;
                float bi = b1[cf];
#pragma unroll
                for (int r = 0; r < 4; ++r) {
                    int rw = mh * 16 + g * 4 + r;
                    float v = fmaxf(acc1b[n][r] + bi, 0.f);
                    *(ushort*)(hidp + rw * 1024 + ((cf * 2) ^ ((rw & 7) << 4))) = f2bf(v);
                }
            }
        }
        // tail: issue W(u+2); wait W(u+1); store into buf[(u+1)&1]
        {
            int k = u + 2;
            bool issued = true;
            if (k < 4)       { if (u & 1) WLOADB(W1t, 256, 0, k);       else WLOADA(W1t, 256, 0, k); }
            else if (k < 8)  { if (u & 1) WLOADB(W1t, 256, 256, k - 4); else WLOADA(W1t, 256, 256, k - 4); }
            else if (k < 16) { if (u & 1) WLOADB(W2t, 512, 0, k - 8);   else WLOADA(W2t, 512, 0, k - 8); }
            else if (WvN)    { if (u & 1) WLOADB(WvN, 256, 0, k - 16);  else WLOADA(WvN, 256, 0, k - 16); }
            else issued = false;
            if (issued) asm volatile("s_waitcnt vmcnt(4)" ::: "memory");
            else        asm volatile("s_waitcnt vmcnt(0)" ::: "memory");
            __builtin_amdgcn_sched_barrier(0);
            if (u < 15 || WvN) { if ((u + 1) & 1) WSTOREB(); else WSTOREA(); }
            asm volatile("s_waitcnt lgkmcnt(0)" ::: "memory");
            __builtin_amdgcn_sched_barrier(0);
            __builtin_amdgcn_s_barrier();
        }
    }

    // ---- LN2 (resid = x1 regs) -> feats fp32+bf16; x2 -> Asp ----
#pragma unroll
    for (int n = 0; n < 4; ++n) {
        int c = cg * 64 + n * 16 + lr;
        float bi = b2[c];
#pragma unroll
        for (int r = 0; r < 4; ++r)
            acc2[n][r] = acc2[n][r] + bi + x1v[n][r];
    }
    {
        float* red1b = (float*)lds;
        float* red2b = (float*)(lds + 512);
        float s1[4] = {0.f, 0.f, 0.f, 0.f}, s2[4] = {0.f, 0.f, 0.f, 0.f};
#pragma unroll
        for (int n = 0; n < 4; ++n)
#pragma unroll
            for (int r = 0; r < 4; ++r) {
                s1[r] += acc2[n][r];
                s2[r] += acc2[n][r] * acc2[n][r];
            }
#pragma unroll
        for (int off = 1; off < 16; off <<= 1) {
#pragma unroll
            for (int r = 0; r < 4; ++r) {
                s1[r] += __shfl_xor(s1[r], off, 64);
                s2[r] += __shfl_xor(s2[r], off, 64);
            }
        }
        if (lr == 0) {
#pragma unroll
            for (int r = 0; r < 4; ++r) {
                red1b[(mh * 16 + g * 4 + r) * 4 + cg] = s1[r];
                red2b[(mh * 16 + g * 4 + r) * 4 + cg] = s2[r];
            }
        }
        __syncthreads();
#pragma unroll
        for (int n = 0; n < 4; ++n) {
            int c = cg * 64 + n * 16 + lr;
            float gg = ln2g[c], bb = ln2b[c];
#pragma unroll
            for (int r = 0; r < 4; ++r) {
                int rr = mh * 16 + g * 4 + r;
                float m1 = red1b[rr * 4] + red1b[rr * 4 + 1] + red1b[rr * 4 + 2] + red1b[rr * 4 + 3];
                float m2 = red2b[rr * 4] + red2b[rr * 4 + 1] + red2b[rr * 4 + 2] + red2b[rr * 4 + 3];
                float mu = m1 * (1.f / 256.f);
                float var = m2 * (1.f / 256.f) - mu * mu;
                float rstd = rsqrtf(var + 1e-5f);
                int row = row0 + rr;
                float o = (acc2[n][r] - mu) * rstd * gg + bb;
                feats[(size_t)row * 256 + c] = o;
                ushort ob = f2bf(o);
                featsb[(size_t)row * 256 + c] = ob;
                *(ushort*)(Asp + rr * 512 + ((2 * c) ^ ((rr & 7) << 4))) = ob;
            }
        }
    }
    __syncthreads();

    // ---- P3: V(l+1) = x2 @ WvN, chunks 16..19; fp8 transposed out ----
    if (WvN) {
        f32x4 acc3[4] = {};
#pragma unroll
        for (int u3 = 0; u3 < 4; ++u3) {
            const char* WB = Wsp + (u3 & 1) * 32768;
            short8 a0 = *(const short8*)(Asp + arow * 512 + ((u3 * 128 + g * 16) ^ sw_a));
            short8 a1 = *(const short8*)(Asp + arow * 512 + ((u3 * 128 + 64 + g * 16) ^ sw_a));
#pragma unroll
            for (int n = 0; n < 4; ++n) {
                int cc = cg * 64 + n * 16 + lr;
                const char* cb = WB + cc * 128;
                int sw = (cc & 7) << 4;
                short8 b0 = *(const short8*)(cb + ((g * 16) ^ sw));
                short8 b1 = *(const short8*)(cb + ((64 + g * 16) ^ sw));
                acc3[n] = MFMA16(a0, b0, acc3[n]);
                acc3[n] = MFMA16(a1, b1, acc3[n]);
            }
            if (u3 < 3) {
                if (u3 < 2) {
                    if (u3 & 1) WLOADB(WvN, 256, 0, u3 + 2);
                    else        WLOADA(WvN, 256, 0, u3 + 2);
                    asm volatile("s_waitcnt vmcnt(4)" ::: "memory");
                } else {
                    asm volatile("s_waitcnt vmcnt(0)" ::: "memory");
                }
                __builtin_amdgcn_sched_barrier(0);
                if ((u3 + 1) & 1) WSTOREB(); else WSTOREA();
                asm volatile("s_waitcnt lgkmcnt(0)" ::: "memory");
                __builtin_amdgcn_sched_barrier(0);
                __builtin_amdgcn_s_barrier();
            }
        }
        __syncthreads();
        uchar* Ts = (uchar*)hidp;   // [256][32] fp8 = 8KB
#pragma unroll
        for (int n = 0; n < 4; ++n) {
            int c = cg * 64 + n * 16 + lr;
            float bi = vbN[c];
            int u = 0;
            u = __builtin_amdgcn_cvt_pk_fp8_f32(acc3[n][0] + bi, acc3[n][1] + bi, u, false);
            u = __builtin_amdgcn_cvt_pk_fp8_f32(acc3[n][2] + bi, acc3[n][3] + bi, u, true);
            *(int*)(Ts + c * 32 + mh * 16 + g * 4) = u;
        }
        __syncthreads();
        if (t < 256) {
            int c = t;
            int b = row0 >> 11;
            int n0 = row0 & 2047;
            uchar* dst = Vt + ((size_t)(b * 256 + c)) * 2048 + n0;
            *(uint4*)dst = *(uint4*)(Ts + c * 32);
            *(uint4*)(dst + 16) = *(uint4*)(Ts + c * 32 + 16);
        }
    }
}

// ---------------------------------------------------------------------------
extern "C" void kernel_launch(void* const* d_in, const int* in_sizes, int n_in,
                              void* d_out, int out_size, void* d_ws, size_t ws_size,
                              hipStream_t stream) {
    const float* lat    = (const float*)d_in[0];
    const float* xc     = (const float*)d_in[1];
    const float* emb    = (const float*)d_in[2];
    const float* in_W   = (const float*)d_in[3];
    const float* in_b   = (const float*)d_in[4];
    const float* val_W  = (const float*)d_in[5];
    const float* val_b  = (const float*)d_in[6];
    const float* attn_W = (const float*)d_in[7];
    const float* attn_b = (const float*)d_in[8];
    const float* ln1_g  = (const float*)d_in[9];
    const float* ln1_b  = (const float*)d_in[10];
    const float* ln2_g  = (const float*)d_in[11];
    const float* ln2_b  = (const float*)d_in[12];
    const float* ffn_W1 = (const float*)d_in[13];
    const float* ffn_b1 = (const float*)d_in[14];
    const float* ffn_W2 = (const float*)d_in[15];
    const float* ffn_b2 = (const float*)d_in[16];
    const float* out_W1 = (const float*)d_in[17];
    const float* out_b1 = (const float*)d_in[18];
    const float* out_W2 = (const float*)d_in[19];
    const float* out_b2 = (const float*)d_in[20];

    char* W = (char*)d_ws;
    float*  feats  = (float*)W;                                // 8 MB
    ushort* featsb = (ushort*)(W + (8u << 20));                // 4 MB
    ushort* attb   = (ushort*)(W + (12u << 20));               // 4 MB
    uchar*  Vt8    = (uchar*)(W + (16u << 20));                // 2 MB fp8
    ushort* wp     = (ushort*)(W + (20u << 20));               // 3.2 MB
    uchar*  E8     = (uchar*)(W + (24u << 20));                // 64 MiB fp8
    ushort* Wvt  = wp;
    ushort* Wat  = wp + 262144;
    ushort* W1t  = wp + 524288;
    ushort* W2t  = wp + 1048576;
    ushort* Wo1t = wp + 1572864;

    setup_all5<<<3872, 256, 0, stream>>>(
        val_W, attn_W, ffn_W1, ffn_W2, out_W1, wp,
        xc, emb, lat, in_W, in_b, feats, featsb, E8);

    gemmM<3><<<R_ / 16, 256, 0, stream>>>(
        featsb, Wvt, val_b, nullptr, nullptr, Vt8, nullptr);

    for (int l = 0; l < LAYERS_; ++l) {
        pv_gemm<<<512, 256, 0, stream>>>(E8, Vt8, attb);
        const ushort* WvN = (l + 1 < LAYERS_) ? (Wvt + (l + 1) * 65536) : nullptr;
        const float* vbN = val_b + ((l + 1 < LAYERS_) ? (l + 1) * 256 : 0);
        gemm_layer<<<R_ / 32, 512, 0, stream>>>(
            attb, Wat + l * 65536, attn_b + l * 256,
            feats, ln1_g + l * 256, ln1_b + l * 256,
            W1t + l * 131072, ffn_b1 + l * 512,
            W2t + l * 131072, ffn_b2 + l * 256,
            ln2_g + l * 256, ln2_b + l * 256,
            featsb, WvN, vbN, Vt8);
    }

    gemmM<4><<<R_ / 16, 256, 0, stream>>>(
        featsb, Wo1t, out_b1, out_W2, out_b2, nullptr, (float*)d_out);
}

// Round 26
// 198.429 us; speedup vs baseline: 1.0205x; 1.0103x over previous
//
#include <hip/hip_runtime.h>

#define B_ 4
#define N_ 2048
#define R_ (B_ * N_)      // 8192 rows
#define HID_ 256
#define EMB_ 64
#define IN_DIM_ 70
#define H_ 4
#define HEAD_ 64
#define FFN_ 512
#define LAYERS_ 4

typedef __attribute__((ext_vector_type(8))) short short8;
typedef __attribute__((ext_vector_type(4))) float f32x4;
typedef unsigned short ushort;
typedef unsigned char uchar;

static __device__ __forceinline__ ushort f2bf(float f) {
    unsigned u = __builtin_bit_cast(unsigned, f);
    u += 0x7fffu + ((u >> 16) & 1u);   // RNE
    return (ushort)(u >> 16);
}
static __device__ __forceinline__ float bf2f(ushort u) {
    unsigned x = ((unsigned)u) << 16;
    return __builtin_bit_cast(float, x);
}

#define GLOAD_LDS16(g, l)                                              \
    __builtin_amdgcn_global_load_lds(                                  \
        (const __attribute__((address_space(1))) void*)(g),            \
        (__attribute__((address_space(3))) void*)(l), 16, 0, 0)

#define MFMA16(a, b, c) __builtin_amdgcn_mfma_f32_16x16x32_bf16(a, b, c, 0, 0, 0)
#define MFMA8(a, b, c) __builtin_amdgcn_mfma_f32_16x16x32_fp8_fp8(a, b, c, 0, 0, 0)

// ---------------------------------------------------------------------------
// setup_all5 (R25): fused ebuild + pack_weights + input_mlp.
// ---------------------------------------------------------------------------
__global__ __launch_bounds__(256) void setup_all5(
        const float* __restrict__ valW, const float* __restrict__ attnW,
        const float* __restrict__ ffnW1, const float* __restrict__ ffnW2,
        const float* __restrict__ outW1, ushort* __restrict__ wp,
        const float* __restrict__ xc, const float* __restrict__ emb,
        const float* __restrict__ lat, const float* __restrict__ W,
        const float* __restrict__ b, float* __restrict__ feats,
        ushort* __restrict__ featsb, uchar* __restrict__ E) {
    __shared__ __align__(16) char smem[9216];
    int blk = blockIdx.x;
    int t = threadIdx.x;

    if (blk < 2048) {
        // ---- ebuild (fp8 E): 32 i x 256 j per block ----
        float4* civ = (float4*)smem;             // 32
        float4* cjv = (float4*)(smem + 512);     // 256
        int f = blk;
        int jb = f & 7, ibl = (f >> 3) & 63, bb2 = f >> 9;
        const float* xb = xc + (size_t)bb2 * N_ * 3;
        if (t < 32) {
            const float* p = &xb[(ibl * 32 + t) * 3];
            float x = p[0], y = p[1], z = p[2];
            civ[t] = make_float4(x, y, z, x * x + y * y + z * z);
        }
        {
            const float* p = &xb[(jb * 256 + t) * 3];
            float x = p[0], y = p[1], z = p[2];
            cjv[t] = make_float4(x, y, z, x * x + y * y + z * z);
        }
        __syncthreads();
        int lane = t & 31, ig = t >> 5;          // lane: 8 j; ig: 4 i
        float4 cj[8];
#pragma unroll
        for (int e = 0; e < 8; ++e) cj[e] = cjv[lane * 8 + e];
        const float ch3 = -0.0625f * 1.44269504088896f;   // h=3: inv=1/16
        uchar* Ebase = E + ((size_t)bb2 * 2048 + ibl * 32) * 2048 + (size_t)jb * 256 + lane * 8;

        for (int r = 0; r < 4; ++r) {
            int i = ig * 4 + r;
            float4 ci = civ[i];
            float ev[8];
#pragma unroll
            for (int e = 0; e < 8; ++e) {
                float d = (ci.w + cj[e].w) -
                          2.f * (ci.x * cj[e].x + ci.y * cj[e].y + ci.z * cj[e].z);
                ev[e] = exp2f(d * ch3);
            }
            uchar* rowp = Ebase + (size_t)i * 2048;
#pragma unroll
            for (int h = 3; h >= 0; --h) {
                int lo = 0, hi = 0;
                lo = __builtin_amdgcn_cvt_pk_fp8_f32(ev[0], ev[1], lo, false);
                lo = __builtin_amdgcn_cvt_pk_fp8_f32(ev[2], ev[3], lo, true);
                hi = __builtin_amdgcn_cvt_pk_fp8_f32(ev[4], ev[5], hi, false);
                hi = __builtin_amdgcn_cvt_pk_fp8_f32(ev[6], ev[7], hi, true);
                uint2 val;
                val.x = (unsigned)lo;
                val.y = (unsigned)hi;
                *(uint2*)(rowp + (size_t)h * 4 * 2048 * 2048) = val;
                if (h > 0) {
#pragma unroll
                    for (int e = 0; e < 8; ++e) {
                        float s = ev[e] * ev[e];
                        ev[e] = s * s;
                    }
                }
            }
        }
    } else if (blk < 2848) {
        // ---- pack_weights: 8 elements per thread ----
        int base = (blk - 2048) * 2048 + t * 8;
#pragma unroll
        for (int e = 0; e < 8; ++e) {
            int idx = base + e;
            float v;
            if (idx < 262144) {
                int l = idx >> 16, c = (idx >> 8) & 255, k = idx & 255;
                v = valW[((l * 4 + (c >> 6)) * 256 + k) * 64 + (c & 63)];
            } else if (idx < 524288) {
                int i2 = idx - 262144;
                int l = i2 >> 16, c = (i2 >> 8) & 255, k = i2 & 255;
                v = attnW[l * 65536 + k * 256 + c];
            } else if (idx < 1048576) {
                int i2 = idx - 524288;
                int l = i2 >> 17, c = (i2 >> 8) & 511, k = i2 & 255;
                v = ffnW1[l * 131072 + k * 512 + c];
            } else if (idx < 1572864) {
                int i2 = idx - 1048576;
                int l = i2 >> 17, c = (i2 >> 9) & 255, k = i2 & 511;
                v = ffnW2[l * 131072 + k * 256 + c];
            } else {
                int i2 = idx - 1572864;
                int c = i2 >> 8, k = i2 & 255;
                v = outW1[k * 256 + c];
            }
            wp[idx] = f2bf(v);
        }
    } else {
        // ---- input_mlp (8 rows per block) ----
        float (*xr)[IN_DIM_ + 2] = (float(*)[IN_DIM_ + 2])smem;
        int row0 = (blk - 2848) * 8;
        for (int idx = t; idx < 8 * IN_DIM_; idx += 256) {
            int r = idx / IN_DIM_, f = idx % IN_DIM_;
            int rr = row0 + r;
            float v;
            if (f < 3)       v = xc[rr * 3 + f];
            else if (f < 67) v = emb[rr * EMB_ + (f - 3)];
            else             v = lat[rr * 3 + (f - 67)];
            xr[r][f] = v;
        }
        __syncthreads();
        float acc[8] = {0.f, 0.f, 0.f, 0.f, 0.f, 0.f, 0.f, 0.f};
        for (int f = 0; f < IN_DIM_; ++f) {
            float w = W[f * HID_ + t];
#pragma unroll
            for (int r = 0; r < 8; ++r) acc[r] += xr[r][f] * w;
        }
        float bb = b[t];
#pragma unroll
        for (int r = 0; r < 8; ++r) {
            float v = fmaxf(acc[r] + bb, 0.f);
            feats[(row0 + r) * HID_ + t] = v;
            featsb[(row0 + r) * HID_ + t] = f2bf(v);
        }
    }
}

// ---------------------------------------------------------------------------
// pv_gemm v6 (R20): fp8 MFMA, 64-row blocks, grid 512, 2 blocks/CU,
// counted vmcnt 4/2/0.
// ---------------------------------------------------------------------------
__global__ __launch_bounds__(256, 2) void pv_gemm(const uchar* __restrict__ E,
                                                  const uchar* __restrict__ Vt,
                                                  ushort* __restrict__ attb) {
    __shared__ __align__(16) char lds[32768];
    int t = threadIdx.x;
    int l = t & 63, w = t >> 6;
    int lr = l & 15, g = l >> 4;

    int f = blockIdx.x;                 // 512 blocks
    int xcd = f & 7, s = f >> 3;        // s 0..63
    int combo = xcd * 2 + (s >> 5);     // 0..15
    int ib = s & 31;                    // 32 i-tiles of 64 rows
    int b = combo & 3, h = combo >> 2;
    int i_base = ib * 64;
    int hc = h * 64;

    const uchar* Eb = E + (size_t)(h * 4 + b) * 2048 * 2048;
    const uchar* VtB = Vt + (size_t)(b * 256 + hc) * 2048;

    const uchar* srcA;
    {
        int row = t >> 2, p = t & 3;
        srcA = Eb + (size_t)(i_base + row) * 2048 + ((p ^ ((row >> 1) & 3)) << 4);
    }
    const uchar* srcV;
    {
        int col = t >> 2, p = t & 3;
        srcV = VtB + (size_t)col * 2048 + ((p ^ ((col >> 1) & 3)) << 4);
    }
    auto STAGE = [&](int c) {
        char* base = lds + (c & 3) * 8192;
        GLOAD_LDS16(srcA + c * 64, base + t * 16);
        GLOAD_LDS16(srcV + c * 64, base + 4096 + t * 16);
    };

    f32x4 acc[4] = {};
    f32x4 accd = {};
    const long ones8 = 0x3838383838383838L;   // 8 x fp8(1.0)

    int r0 = w * 16 + lr;

    auto COMPUTE = [&](int c) {
        const char* As = lds + (c & 3) * 8192;
        const char* Vs = As + 4096;
#pragma unroll
        for (int kk = 0; kk < 2; ++kk) {
            int off = kk * 32 + g * 8;
            long a0 = *(const long*)(As + r0 * 64 + (off ^ (((r0 >> 1) & 3) << 4)));
            accd = MFMA8(a0, ones8, accd);
#pragma unroll
            for (int n = 0; n < 4; ++n) {
                int col = n * 16 + lr;
                long bv = *(const long*)(Vs + col * 64 + (off ^ (((col >> 1) & 3) << 4)));
                acc[n] = MFMA8(a0, bv, acc[n]);
            }
        }
    };

    STAGE(0);
    STAGE(1);
    STAGE(2);

    for (int c = 0; c < 30; ++c) {
        asm volatile("s_waitcnt vmcnt(4)" ::: "memory");
        __builtin_amdgcn_s_barrier();
        __builtin_amdgcn_sched_barrier(0);
        if (c < 29) STAGE(c + 3);
        COMPUTE(c);
    }
    asm volatile("s_waitcnt vmcnt(2)" ::: "memory");
    __builtin_amdgcn_s_barrier();
    __builtin_amdgcn_sched_barrier(0);
    COMPUTE(30);
    asm volatile("s_waitcnt vmcnt(0)" ::: "memory");
    __builtin_amdgcn_s_barrier();
    __builtin_amdgcn_sched_barrier(0);
    COMPUTE(31);

#pragma unroll
    for (int r = 0; r < 4; ++r) {
        float invd = 1.f / (accd[r] + 1e-8f);
        int row = i_base + w * 16 + g * 4 + r;
        size_t rb = ((size_t)b * N_ + row) * 256 + hc + lr;
#pragma unroll
        for (int n = 0; n < 4; ++n)
            attb[rb + n * 16] = f2bf(acc[n][r] * invd);
    }
}

// ---------------------------------------------------------------------------
// gemmM<3>: V-proj layer 0 (LDS-dbuf staged A+B, KD=256, fp8 transposed out).
// ---------------------------------------------------------------------------
__global__ __launch_bounds__(256) void gemmV0(const ushort* __restrict__ A,
                                              const ushort* __restrict__ Bt,
                                              const float* __restrict__ bias,
                                              uchar* __restrict__ outb) {
    __shared__ __align__(16) char lds[69632];
    int t = threadIdx.x;
    int l = t & 63, w = t >> 6;
    int lr = l & 15, g = l >> 4;
    int row0 = blockIdx.x * 16;
    f32x4 acc[4] = {};

    const ushort* srcA = A + (size_t)(row0 + (t >> 3)) * 256 + (((t & 7) ^ ((t >> 3) & 7)) << 3);
    const ushort* srcB[8];
#pragma unroll
    for (int q = 0; q < 8; ++q) {
        int cl = q * 32 + (t >> 3);
        srcB[q] = Bt + (size_t)cl * 256 + (((t & 7) ^ (cl & 7)) << 3);
    }
    auto STAGE = [&](int buf) {
        if (t < 128) GLOAD_LDS16(srcA, lds + buf * 2048 + t * 16);
#pragma unroll
        for (int q = 0; q < 8; ++q)
            GLOAD_LDS16(srcB[q], lds + 4096 + buf * 32768 + q * 4096 + t * 16);
        srcA += 64;
#pragma unroll
        for (int q = 0; q < 8; ++q) srcB[q] += 64;
    };

    int sw_a = (lr & 7) << 4;
    int aoff = lr * 128;

    STAGE(0);
#pragma unroll
    for (int c = 0; c < 4; ++c) {
        __syncthreads();
        if (c + 1 < 4) STAGE((c + 1) & 1);
        const char* As = lds + (c & 1) * 2048;
        const char* Ws = lds + 4096 + (c & 1) * 32768;

        short8 a0 = *(const short8*)(As + aoff + ((g * 16) ^ sw_a));
        short8 a1 = *(const short8*)(As + aoff + ((64 + g * 16) ^ sw_a));
#pragma unroll
        for (int n = 0; n < 4; ++n) {
            int cc = w * 64 + n * 16 + lr;
            const char* cb = Ws + cc * 128;
            int sw = (cc & 7) << 4;
            short8 b0 = *(const short8*)(cb + ((g * 16) ^ sw));
            short8 b1 = *(const short8*)(cb + ((64 + g * 16) ^ sw));
            acc[n] = MFMA16(a0, b0, acc[n]);
            acc[n] = MFMA16(a1, b1, acc[n]);
        }
    }
    __syncthreads();

    uchar* Ts = (uchar*)(lds + 8192);   // [256][16] fp8
#pragma unroll
    for (int n = 0; n < 4; ++n) {
        int c = w * 64 + n * 16 + lr;
        float bi = bias[c];
        int u = 0;
        u = __builtin_amdgcn_cvt_pk_fp8_f32(acc[n][0] + bi, acc[n][1] + bi, u, false);
        u = __builtin_amdgcn_cvt_pk_fp8_f32(acc[n][2] + bi, acc[n][3] + bi, u, true);
        *(int*)(Ts + c * 16 + g * 4) = u;
    }
    __syncthreads();
    {
        int c = t;
        int b = row0 >> 11;
        int n0 = row0 & 2047;
        *(uint4*)(outb + ((size_t)(b * 256 + c)) * 2048 + n0) = *(uint4*)(Ts + c * 16);
    }
}

// ---------------------------------------------------------------------------
// gemm_layer v6: R25 v5 + fused final out-MLP. When dout != nullptr (last
// layer), P3 computes x2 @ WvN(=Wo1t) + relu(+out_b1), then the 3-col
// projection @W2f + b2f -> dout (bit-identical to old gemmM<4>).
// ---------------------------------------------------------------------------
__global__ __launch_bounds__(512) void gemm_layer(
        const ushort* __restrict__ attb,
        const ushort* __restrict__ Wat, const float* __restrict__ pb,
        float* __restrict__ feats,
        const float* __restrict__ ln1g, const float* __restrict__ ln1b,
        const ushort* __restrict__ W1t, const float* __restrict__ b1,
        const ushort* __restrict__ W2t, const float* __restrict__ b2,
        const float* __restrict__ ln2g, const float* __restrict__ ln2b,
        ushort* __restrict__ featsb,
        const ushort* __restrict__ WvN, const float* __restrict__ vbN,
        uchar* __restrict__ Vt,
        const float* __restrict__ W2f, const float* __restrict__ b2f,
        float* __restrict__ dout) {
    __shared__ __align__(16) char lds[122880];
    char* Aa = lds;              // 8KB (2x4KB); red overlay after P0
    char* Asp = lds + 8192;      // 16KB: x1 / x2 bf16 (32 rows x 512B)
    char* Wsp = lds + 24576;     // 2 x 32KB
    char* hidp = lds + 90112;    // 32KB (32 rows x 1024B); Ts overlay in P3

    int t = threadIdx.x;
    int l = t & 63, w = t >> 6;
    int cg = w & 3, mh = w >> 2;
    int lr = l & 15, g = l >> 4;
    int row0 = blockIdx.x * 32;
    int arow = mh * 16 + lr;
    int sw_a = (lr & 7) << 4;
    int trow = t >> 3, slot = t & 7;

    uint4 wA0, wA1, wA2, wA3;   // set A  <-> Wsp buf 0
    uint4 wB0, wB1, wB2, wB3;   // set B  <-> Wsp buf 1
    auto WLOADA = [&](const ushort* Wb, int stride, int colbase, int c) {
        const ushort* base = Wb + c * 64;
#pragma unroll
        for (int q = 0; q < 4; ++q) {
            int cl = colbase + q * 64 + trow;
            uint4 v = *(const uint4*)(base + (size_t)cl * stride + ((slot ^ (cl & 7)) << 3));
            if (q == 0) wA0 = v; else if (q == 1) wA1 = v;
            else if (q == 2) wA2 = v; else wA3 = v;
        }
    };
    auto WLOADB = [&](const ushort* Wb, int stride, int colbase, int c) {
        const ushort* base = Wb + c * 64;
#pragma unroll
        for (int q = 0; q < 4; ++q) {
            int cl = colbase + q * 64 + trow;
            uint4 v = *(const uint4*)(base + (size_t)cl * stride + ((slot ^ (cl & 7)) << 3));
            if (q == 0) wB0 = v; else if (q == 1) wB1 = v;
            else if (q == 2) wB2 = v; else wB3 = v;
        }
    };
    auto WSTOREA = [&]() {
        *(uint4*)(Wsp + 0 * 8192 + t * 16) = wA0;
        *(uint4*)(Wsp + 1 * 8192 + t * 16) = wA1;
        *(uint4*)(Wsp + 2 * 8192 + t * 16) = wA2;
        *(uint4*)(Wsp + 3 * 8192 + t * 16) = wA3;
    };
    auto WSTOREB = [&]() {
        char* base = Wsp + 32768;
        *(uint4*)(base + 0 * 8192 + t * 16) = wB0;
        *(uint4*)(base + 1 * 8192 + t * 16) = wB1;
        *(uint4*)(base + 2 * 8192 + t * 16) = wB2;
        *(uint4*)(base + 3 * 8192 + t * 16) = wB3;
    };

    // ---- P0: attn-proj (KD=256), 2-barrier form, Wsp buf0, set A ----
    const ushort* srcA = attb + (size_t)(row0 + trow) * 256 + ((slot ^ (trow & 7)) << 3);
    auto STAGEA = [&](int buf, int c) {
        if (t < 256) GLOAD_LDS16(srcA + c * 64, Aa + buf * 4096 + t * 16);
    };

    f32x4 acc0[4] = {};
    STAGEA(0, 0);
    WLOADA(Wat, 256, 0, 0);
#pragma unroll
    for (int c = 0; c < 4; ++c) {
        __syncthreads();
        WSTOREA();
        __syncthreads();
        if (c < 3) { WLOADA(Wat, 256, 0, c + 1); STAGEA((c + 1) & 1, c + 1); }
        else WLOADA(W1t, 256, 0, 0);       // W(0) of the P1/P2 pipeline

        const char* As = Aa + (c & 1) * 4096;
        short8 a0 = *(const short8*)(As + arow * 128 + ((g * 16) ^ sw_a));
        short8 a1 = *(const short8*)(As + arow * 128 + ((64 + g * 16) ^ sw_a));
#pragma unroll
        for (int n = 0; n < 4; ++n) {
            int cc = cg * 64 + n * 16 + lr;
            const char* cb = Wsp + cc * 128;
            int sw = (cc & 7) << 4;
            short8 b0 = *(const short8*)(cb + ((g * 16) ^ sw));
            short8 b1 = *(const short8*)(cb + ((64 + g * 16) ^ sw));
            acc0[n] = MFMA16(a0, b0, acc0[n]);
            acc0[n] = MFMA16(a1, b1, acc0[n]);
        }
    }
    __syncthreads();

    // ---- LN1 (x1 in regs; bf16 -> Asp) ----
    float* red1 = (float*)lds;          // [32][4]
    float* red2 = (float*)(lds + 512);
    float x1v[4][4];
    {
        float s1[4] = {0.f, 0.f, 0.f, 0.f}, s2[4] = {0.f, 0.f, 0.f, 0.f};
#pragma unroll
        for (int n = 0; n < 4; ++n) {
            int c = cg * 64 + n * 16 + lr;
            float bi = pb[c];
#pragma unroll
            for (int r = 0; r < 4; ++r) {
                int row = row0 + mh * 16 + g * 4 + r;
                float v = acc0[n][r] + bi + feats[(size_t)row * 256 + c];
                x1v[n][r] = v;
                s1[r] += v;
                s2[r] += v * v;
            }
        }
#pragma unroll
        for (int off = 1; off < 16; off <<= 1) {
#pragma unroll
            for (int r = 0; r < 4; ++r) {
                s1[r] += __shfl_xor(s1[r], off, 64);
                s2[r] += __shfl_xor(s2[r], off, 64);
            }
        }
        if (lr == 0) {
#pragma unroll
            for (int r = 0; r < 4; ++r) {
                red1[(mh * 16 + g * 4 + r) * 4 + cg] = s1[r];
                red2[(mh * 16 + g * 4 + r) * 4 + cg] = s2[r];
            }
        }
        __syncthreads();
#pragma unroll
        for (int n = 0; n < 4; ++n) {
            int c = cg * 64 + n * 16 + lr;
            float gg = ln1g[c], bb = ln1b[c];
#pragma unroll
            for (int r = 0; r < 4; ++r) {
                int rr = mh * 16 + g * 4 + r;
                float m1 = red1[rr * 4] + red1[rr * 4 + 1] + red1[rr * 4 + 2] + red1[rr * 4 + 3];
                float m2 = red2[rr * 4] + red2[rr * 4 + 1] + red2[rr * 4 + 2] + red2[rr * 4 + 3];
                float mu = m1 * (1.f / 256.f);
                float var = m2 * (1.f / 256.f) - mu * mu;
                float rstd = rsqrtf(var + 1e-5f);
                float o = (x1v[n][r] - mu) * rstd * gg + bb;
                x1v[n][r] = o;
                *(ushort*)(Asp + rr * 512 + ((2 * c) ^ ((rr & 7) << 4))) = f2bf(o);
            }
        }
    }

    // ---- P1+P2 pipeline prologue: Wsp[0]=W(0); issue W(1)->set B ----
    WSTOREA();
    WLOADB(W1t, 256, 0, 1);
    asm volatile("s_waitcnt lgkmcnt(0)" ::: "memory");
    __builtin_amdgcn_sched_barrier(0);
    __builtin_amdgcn_s_barrier();

    f32x4 acc1[4] = {}, acc1b[4] = {}, acc2[4] = {};
#pragma unroll
    for (int u = 0; u < 16; ++u) {
        const char* WB = Wsp + (u & 1) * 32768;
        short8 a0, a1;
        if (u < 8) {
            int c = u & 3;
            a0 = *(const short8*)(Asp + arow * 512 + ((c * 128 + g * 16) ^ sw_a));
            a1 = *(const short8*)(Asp + arow * 512 + ((c * 128 + 64 + g * 16) ^ sw_a));
        } else {
            int c = u - 8;
            a0 = *(const short8*)(hidp + arow * 1024 + ((c * 128 + g * 16) ^ sw_a));
            a1 = *(const short8*)(hidp + arow * 1024 + ((c * 128 + 64 + g * 16) ^ sw_a));
        }
#pragma unroll
        for (int n = 0; n < 4; ++n) {
            int cc = cg * 64 + n * 16 + lr;
            const char* cb = WB + cc * 128;
            int sw = (cc & 7) << 4;
            short8 b0 = *(const short8*)(cb + ((g * 16) ^ sw));
            short8 b1 = *(const short8*)(cb + ((64 + g * 16) ^ sw));
            if (u < 4)      { acc1[n] = MFMA16(a0, b0, acc1[n]);  acc1[n] = MFMA16(a1, b1, acc1[n]); }
            else if (u < 8) { acc1b[n] = MFMA16(a0, b0, acc1b[n]); acc1b[n] = MFMA16(a1, b1, acc1b[n]); }
            else            { acc2[n] = MFMA16(a0, b0, acc2[n]);  acc2[n] = MFMA16(a1, b1, acc2[n]); }
        }
        if (u == 3) {
#pragma unroll
            for (int n = 0; n < 4; ++n) {
                int cf = cg * 64 + n * 16 + lr;
                float bi = b1[cf];
#pragma unroll
                for (int r = 0; r < 4; ++r) {
                    int rw = mh * 16 + g * 4 + r;
                    float v = fmaxf(acc1[n][r] + bi, 0.f);
                    *(ushort*)(hidp + rw * 1024 + ((cf * 2) ^ ((rw & 7) << 4))) = f2bf(v);
                }
            }
        }
        if (u == 7) {
#pragma unroll
            for (int n = 0; n < 4; ++n) {
                int cf = 256 + cg * 64 + n * 16 + lr;
                float bi = b1[cf];
#pragma unroll
                for (int r = 0; r < 4; ++r) {
                    int rw = mh * 16 + g * 4 + r;
                    float v = fmaxf(acc1b[n][r] + bi, 0.f);
                    *(ushort*)(hidp + rw * 1024 + ((cf * 2) ^ ((rw & 7) << 4))) = f2bf(v);
                }
            }
        }
        // tail: issue W(u+2); wait W(u+1); store into buf[(u+1)&1]
        {
            int k = u + 2;
            bool issued = true;
            if (k < 4)       { if (u & 1) WLOADB(W1t, 256, 0, k);       else WLOADA(W1t, 256, 0, k); }
            else if (k < 8)  { if (u & 1) WLOADB(W1t, 256, 256, k - 4); else WLOADA(W1t, 256, 256, k - 4); }
            else if (k < 16) { if (u & 1) WLOADB(W2t, 512, 0, k - 8);   else WLOADA(W2t, 512, 0, k - 8); }
            else if (WvN)    { if (u & 1) WLOADB(WvN, 256, 0, k - 16);  else WLOADA(WvN, 256, 0, k - 16); }
            else issued = false;
            if (issued) asm volatile("s_waitcnt vmcnt(4)" ::: "memory");
            else        asm volatile("s_waitcnt vmcnt(0)" ::: "memory");
            __builtin_amdgcn_sched_barrier(0);
            if (u < 15 || WvN) { if ((u + 1) & 1) WSTOREB(); else WSTOREA(); }
            asm volatile("s_waitcnt lgkmcnt(0)" ::: "memory");
            __builtin_amdgcn_sched_barrier(0);
            __builtin_amdgcn_s_barrier();
        }
    }

    // ---- LN2 (resid = x1 regs) -> feats fp32+bf16; x2 -> Asp ----
#pragma unroll
    for (int n = 0; n < 4; ++n) {
        int c = cg * 64 + n * 16 + lr;
        float bi = b2[c];
#pragma unroll
        for (int r = 0; r < 4; ++r)
            acc2[n][r] = acc2[n][r] + bi + x1v[n][r];
    }
    {
        float* red1b = (float*)lds;
        float* red2b = (float*)(lds + 512);
        float s1[4] = {0.f, 0.f, 0.f, 0.f}, s2[4] = {0.f, 0.f, 0.f, 0.f};
#pragma unroll
        for (int n = 0; n < 4; ++n)
#pragma unroll
            for (int r = 0; r < 4; ++r) {
                s1[r] += acc2[n][r];
                s2[r] += acc2[n][r] * acc2[n][r];
            }
#pragma unroll
        for (int off = 1; off < 16; off <<= 1) {
#pragma unroll
            for (int r = 0; r < 4; ++r) {
                s1[r] += __shfl_xor(s1[r], off, 64);
                s2[r] += __shfl_xor(s2[r], off, 64);
            }
        }
        if (lr == 0) {
#pragma unroll
            for (int r = 0; r < 4; ++r) {
                red1b[(mh * 16 + g * 4 + r) * 4 + cg] = s1[r];
                red2b[(mh * 16 + g * 4 + r) * 4 + cg] = s2[r];
            }
        }
        __syncthreads();
#pragma unroll
        for (int n = 0; n < 4; ++n) {
            int c = cg * 64 + n * 16 + lr;
            float gg = ln2g[c], bb = ln2b[c];
#pragma unroll
            for (int r = 0; r < 4; ++r) {
                int rr = mh * 16 + g * 4 + r;
                float m1 = red1b[rr * 4] + red1b[rr * 4 + 1] + red1b[rr * 4 + 2] + red1b[rr * 4 + 3];
                float m2 = red2b[rr * 4] + red2b[rr * 4 + 1] + red2b[rr * 4 + 2] + red2b[rr * 4 + 3];
                float mu = m1 * (1.f / 256.f);
                float var = m2 * (1.f / 256.f) - mu * mu;
                float rstd = rsqrtf(var + 1e-5f);
                int row = row0 + rr;
                float o = (acc2[n][r] - mu) * rstd * gg + bb;
                feats[(size_t)row * 256 + c] = o;
                ushort ob = f2bf(o);
                featsb[(size_t)row * 256 + c] = ob;
                *(ushort*)(Asp + rr * 512 + ((2 * c) ^ ((rr & 7) << 4))) = ob;
            }
        }
    }
    __syncthreads();

    // ---- P3: x2 @ WvN (KD=256), 4 chunks; then either V-proj store or
    //      (dout) fused out-MLP projection ----
    if (WvN) {
        f32x4 acc3[4] = {};
#pragma unroll
        for (int u3 = 0; u3 < 4; ++u3) {
            const char* WB = Wsp + (u3 & 1) * 32768;
            short8 a0 = *(const short8*)(Asp + arow * 512 + ((u3 * 128 + g * 16) ^ sw_a));
            short8 a1 = *(const short8*)(Asp + arow * 512 + ((u3 * 128 + 64 + g * 16) ^ sw_a));
#pragma unroll
            for (int n = 0; n < 4; ++n) {
                int cc = cg * 64 + n * 16 + lr;
                const char* cb = WB + cc * 128;
                int sw = (cc & 7) << 4;
                short8 b0 = *(const short8*)(cb + ((g * 16) ^ sw));
                short8 b1 = *(const short8*)(cb + ((64 + g * 16) ^ sw));
                acc3[n] = MFMA16(a0, b0, acc3[n]);
                acc3[n] = MFMA16(a1, b1, acc3[n]);
            }
            if (u3 < 3) {
                if (u3 < 2) {
                    if (u3 & 1) WLOADB(WvN, 256, 0, u3 + 2);
                    else        WLOADA(WvN, 256, 0, u3 + 2);
                    asm volatile("s_waitcnt vmcnt(4)" ::: "memory");
                } else {
                    asm volatile("s_waitcnt vmcnt(0)" ::: "memory");
                }
                __builtin_amdgcn_sched_barrier(0);
                if ((u3 + 1) & 1) WSTOREB(); else WSTOREA();
                asm volatile("s_waitcnt lgkmcnt(0)" ::: "memory");
                __builtin_amdgcn_sched_barrier(0);
                __builtin_amdgcn_s_barrier();
            }
        }
        __syncthreads();
        if (dout == nullptr) {
            // V(l+1) fp8 transposed out
            uchar* Ts = (uchar*)hidp;   // [256][32] fp8 = 8KB
#pragma unroll
            for (int n = 0; n < 4; ++n) {
                int c = cg * 64 + n * 16 + lr;
                float bi = vbN[c];
                int u = 0;
                u = __builtin_amdgcn_cvt_pk_fp8_f32(acc3[n][0] + bi, acc3[n][1] + bi, u, false);
                u = __builtin_amdgcn_cvt_pk_fp8_f32(acc3[n][2] + bi, acc3[n][3] + bi, u, true);
                *(int*)(Ts + c * 32 + mh * 16 + g * 4) = u;
            }
            __syncthreads();
            if (t < 256) {
                int c = t;
                int b = row0 >> 11;
                int n0 = row0 & 2047;
                uchar* dst = Vt + ((size_t)(b * 256 + c)) * 2048 + n0;
                *(uint4*)dst = *(uint4*)(Ts + c * 32);
                *(uint4*)(dst + 16) = *(uint4*)(Ts + c * 32 + 16);
            }
        } else {
            // fused final out-MLP: relu -> Ts bf16 -> @W2f + b2f -> dout
            ushort(*Ts)[264] = (ushort(*)[264])hidp;   // [32][264] = 16.5KB
#pragma unroll
            for (int n = 0; n < 4; ++n) {
                int c = cg * 64 + n * 16 + lr;
                float bi = vbN[c];
#pragma unroll
                for (int r = 0; r < 4; ++r)
                    Ts[mh * 16 + g * 4 + r][c] = f2bf(fmaxf(acc3[n][r] + bi, 0.f));
            }
            __syncthreads();
            int row = t >> 4, sg = t & 15;   // 32 rows x 16 lanes
            float p0 = 0.f, p1 = 0.f, p2 = 0.f;
#pragma unroll
            for (int e = 0; e < 16; ++e) {
                float x = bf2f(Ts[row][sg * 16 + e]);
                const float* wr = &W2f[(sg * 16 + e) * 3];
                p0 += x * wr[0];
                p1 += x * wr[1];
                p2 += x * wr[2];
            }
#pragma unroll
            for (int off = 1; off < 16; off <<= 1) {
                p0 += __shfl_xor(p0, off, 64);
                p1 += __shfl_xor(p1, off, 64);
                p2 += __shfl_xor(p2, off, 64);
            }
            if (sg == 0) {
                int gr = row0 + row;
                dout[gr * 3 + 0] = p0 + b2f[0];
                dout[gr * 3 + 1] = p1 + b2f[1];
                dout[gr * 3 + 2] = p2 + b2f[2];
            }
        }
    }
}

// ---------------------------------------------------------------------------
extern "C" void kernel_launch(void* const* d_in, const int* in_sizes, int n_in,
                              void* d_out, int out_size, void* d_ws, size_t ws_size,
                              hipStream_t stream) {
    const float* lat    = (const float*)d_in[0];
    const float* xc     = (const float*)d_in[1];
    const float* emb    = (const float*)d_in[2];
    const float* in_W   = (const float*)d_in[3];
    const float* in_b   = (const float*)d_in[4];
    const float* val_W  = (const float*)d_in[5];
    const float* val_b  = (const float*)d_in[6];
    const float* attn_W = (const float*)d_in[7];
    const float* attn_b = (const float*)d_in[8];
    const float* ln1_g  = (const float*)d_in[9];
    const float* ln1_b  = (const float*)d_in[10];
    const float* ln2_g  = (const float*)d_in[11];
    const float* ln2_b  = (const float*)d_in[12];
    const float* ffn_W1 = (const float*)d_in[13];
    const float* ffn_b1 = (const float*)d_in[14];
    const float* ffn_W2 = (const float*)d_in[15];
    const float* ffn_b2 = (const float*)d_in[16];
    const float* out_W1 = (const float*)d_in[17];
    const float* out_b1 = (const float*)d_in[18];
    const float* out_W2 = (const float*)d_in[19];
    const float* out_b2 = (const float*)d_in[20];

    char* W = (char*)d_ws;
    float*  feats  = (float*)W;                                // 8 MB
    ushort* featsb = (ushort*)(W + (8u << 20));                // 4 MB
    ushort* attb   = (ushort*)(W + (12u << 20));               // 4 MB
    uchar*  Vt8    = (uchar*)(W + (16u << 20));                // 2 MB fp8
    ushort* wp     = (ushort*)(W + (20u << 20));               // 3.2 MB
    uchar*  E8     = (uchar*)(W + (24u << 20));                // 64 MiB fp8
    ushort* Wvt  = wp;
    ushort* Wat  = wp + 262144;
    ushort* W1t  = wp + 524288;
    ushort* W2t  = wp + 1048576;
    ushort* Wo1t = wp + 1572864;

    setup_all5<<<3872, 256, 0, stream>>>(
        val_W, attn_W, ffn_W1, ffn_W2, out_W1, wp,
        xc, emb, lat, in_W, in_b, feats, featsb, E8);

    gemmV0<<<R_ / 16, 256, 0, stream>>>(featsb, Wvt, val_b, Vt8);

    for (int l = 0; l < LAYERS_; ++l) {
        pv_gemm<<<512, 256, 0, stream>>>(E8, Vt8, attb);
        bool last = (l + 1 == LAYERS_);
        const ushort* WvN = last ? Wo1t : (Wvt + (l + 1) * 65536);
        const float* vbN = last ? out_b1 : (val_b + (l + 1) * 256);
        gemm_layer<<<R_ / 32, 512, 0, stream>>>(
            attb, Wat + l * 65536, attn_b + l * 256,
            feats, ln1_g + l * 256, ln1_b + l * 256,
            W1t + l * 131072, ffn_b1 + l * 512,
            W2t + l * 131072, ffn_b2 + l * 256,
            ln2_g + l * 256, ln2_b + l * 256,
            featsb, WvN, vbN, Vt8,
            last ? out_W2 : nullptr, last ? out_b2 : nullptr,
            last ? (float*)d_out : nullptr);
    }
}